// Round 3
// baseline (366.263 us; speedup 1.0000x reference)
//
#include <hip/hip_runtime.h>
#include <cstdint>
#include <cstddef>

#define NPIX 9216          // 96*96
#define NB 2
#define NC 256
#define RC 64
#define TK 16
#define NROWS (NB * NPIX)  // 18432
#define CT 128             // cols per LDS tile
#define NQ 8               // col splits per batch
#define ECOLS 1152         // cols per split
#define NTE 9              // tiles per split
#define NCHUNK 128         // per-row chunk-maxima streams (q*16 + wave*4 + quad)
#define MAXC 128           // compact candidate slots per row
#define MARGIN 0.008f      // 2*e, e <= 2.01*2^-9 * ||a||*||b|| = 3.93e-3

typedef unsigned short ushort_t;
typedef unsigned int uint_t;
typedef __bf16 bf16x8 __attribute__((ext_vector_type(8)));
typedef float f32x4 __attribute__((ext_vector_type(4)));

__device__ __forceinline__ uint_t f2bf(float x) {
  uint_t u = __float_as_uint(x);
  return (u + 0x7FFFu + ((u >> 16) & 1u)) >> 16;
}

// monotone float->uint map (bigger float => bigger uint)
__device__ __forceinline__ uint_t ordu(float v) {
  uint_t u = __float_as_uint(v);
  return (u & 0x80000000u) ? ~u : (u | 0x80000000u);
}

// ---------------- K1: 1x1 conv reduce, c-split partials ----------------
// grid: 72 pixgroups x 4 rq x 4 cq = 1152. feat4 layout [rq*4+cq][NROWS][16]
__global__ __launch_bounds__(256) void k_reduce(
    const float* __restrict__ x, const float* __restrict__ wr,
    float* __restrict__ feat4) {
  __shared__ float wl[64 * 16];  // 4 KB: [c_local][r_local]
  const int bi = blockIdx.x;
  const int pg = bi >> 4, rq = (bi >> 2) & 3, cq = bi & 3;
  const int tid = threadIdx.x;
  {
    const int cl = tid >> 2, rg = (tid & 3) * 4;
#pragma unroll
    for (int i = 0; i < 4; ++i)
      wl[cl * 16 + rg + i] = wr[(size_t)(rq * 16 + rg + i) * NC + cq * 64 + cl];
  }
  __syncthreads();

  const int p = pg * 256 + tid;
  const int b = p >= NPIX;
  const int n = p - b * NPIX;
  const float* xp = x + (size_t)b * NC * NPIX + (size_t)cq * 64 * NPIX + n;

  float4 acc[4];
#pragma unroll
  for (int i = 0; i < 4; ++i) acc[i] = make_float4(0.f, 0.f, 0.f, 0.f);

  for (int c = 0; c < 64; ++c) {
    const float xv = xp[(size_t)c * NPIX];           // coalesced
    const float4* w4 = (const float4*)(wl + c * 16); // broadcast
#pragma unroll
    for (int i = 0; i < 4; ++i) {
      float4 w = w4[i];
      acc[i].x += w.x * xv; acc[i].y += w.y * xv;
      acc[i].z += w.z * xv; acc[i].w += w.w * xv;
    }
  }
  float4* o = (float4*)(feat4 + (((size_t)(rq * 4 + cq)) * NROWS + p) * 16);
#pragma unroll
  for (int i = 0; i < 4; ++i) o[i] = acc[i];  // 64B/lane contiguous
}

// ---------------- K1b: sum partials + normalize + bf16 hi ----------------
__global__ __launch_bounds__(256) void k_normsplit(
    const float* __restrict__ feat4, float* __restrict__ nf,
    ushort_t* __restrict__ hi) {
  const int t = blockIdx.x * 256 + threadIdx.x;
  const int p = t >> 2, q = t & 3;  // 4 lanes per pixel
  float4 v[4];
#pragma unroll
  for (int i = 0; i < 4; ++i) v[i] = make_float4(0.f, 0.f, 0.f, 0.f);
#pragma unroll
  for (int pt = 0; pt < 4; ++pt) {
    const float4* fp = (const float4*)(feat4 + (((size_t)(q * 4 + pt)) * NROWS + p) * 16);
#pragma unroll
    for (int i = 0; i < 4; ++i) {
      float4 a = fp[i];
      v[i].x += a.x; v[i].y += a.y; v[i].z += a.z; v[i].w += a.w;
    }
  }
  float ssq = 0.f;
#pragma unroll
  for (int i = 0; i < 4; ++i)
    ssq += v[i].x * v[i].x + v[i].y * v[i].y + v[i].z * v[i].z + v[i].w * v[i].w;
  ssq += __shfl_xor(ssq, 1);
  ssq += __shfl_xor(ssq, 2);
  const float inv = 1.f / fmaxf(sqrtf(ssq), 1e-12f);

  float s[16];
#pragma unroll
  for (int i = 0; i < 4; ++i) {
    s[i * 4 + 0] = v[i].x * inv; s[i * 4 + 1] = v[i].y * inv;
    s[i * 4 + 2] = v[i].z * inv; s[i * 4 + 3] = v[i].w * inv;
  }
  float4* no = (float4*)(nf + (size_t)p * RC + q * 16);
#pragma unroll
  for (int i = 0; i < 4; ++i)
    no[i] = make_float4(s[i * 4], s[i * 4 + 1], s[i * 4 + 2], s[i * 4 + 3]);

  uint_t hs[16];
#pragma unroll
  for (int i = 0; i < 16; ++i) hs[i] = f2bf(s[i]);
  uint4* ho = (uint4*)(hi + (size_t)p * RC + q * 16);
#pragma unroll
  for (int h = 0; h < 2; ++h)
    ho[h] = make_uint4(hs[h*8+0] | (hs[h*8+1] << 16), hs[h*8+2] | (hs[h*8+3] << 16),
                       hs[h*8+4] | (hs[h*8+5] << 16), hs[h*8+6] | (hs[h*8+7] << 16));
}

// Stage one 128x64 bf16 tile (16 KB), reg-staged with XOR-swizzled ds_write:
// LDS slot s of row r holds global slot s^(r&7)  (slot = 16B).
__device__ __forceinline__ void stage_tile(
    const ushort_t* __restrict__ nf_hi, size_t cbase, int cb,
    ushort_t* sh, int tid) {
  const int srow = tid >> 1, shalf = tid & 1;
  const uint4* g4 = (const uint4*)(nf_hi + (cbase + (size_t)(cb + srow)) * 64 + shalf * 32);
  uint4 v0 = g4[0], v1 = g4[1], v2 = g4[2], v3 = g4[3];
  ushort_t* rowp = sh + srow * 64;
  const int rx = srow & 7;
  *(uint4*)(rowp + (((shalf * 4 + 0) ^ rx) * 8)) = v0;
  *(uint4*)(rowp + (((shalf * 4 + 1) ^ rx) * 8)) = v1;
  *(uint4*)(rowp + (((shalf * 4 + 2) ^ rx) * 8)) = v2;
  *(uint4*)(rowp + (((shalf * 4 + 3) ^ rx) * 8)) = v3;
}

// ---------------- K2a: pass A — hi sims, per-lane stream maxima ----------------
// grid: 144 rowblocks(128 rows) x 8 col-splits = 1152.
// Each wave holds ALL 128 rows' B-fragments in regs (8 groups) and owns 2
// column-subtiles per LDS tile: 4 ds_read_b128 feed 32 MFMA (8:1 MFMA:ds).
__global__ __launch_bounds__(256) void k_sim_max(
    const ushort_t* __restrict__ nf_hi, float* __restrict__ tmax) {
  __shared__ ushort_t sh[CT * 64];  // 16 KB
  const int rb = blockIdx.x >> 3, q = blockIdx.x & 7;
  const int tid = threadIdx.x, wave = tid >> 6, lane = tid & 63;
  const int n = lane & 15, quad = lane >> 4;
  const int rowbase = rb * 128 + n;
  const int b = rb >= 72;
  const size_t cbase = (size_t)b * NPIX;

  bf16x8 bh0[8], bh1[8];
#pragma unroll
  for (int g = 0; g < 8; ++g) {
    const ushort_t* rp = nf_hi + (size_t)(rowbase + g * 16) * 64;
    bh0[g] = *(const bf16x8*)(rp + quad * 8);
    bh1[g] = *(const bf16x8*)(rp + 32 + quad * 8);
  }

  const int x0 = (quad ^ (n & 7)) * 8;        // swizzled slot offsets (ushorts)
  const int x1 = ((quad + 4) ^ (n & 7)) * 8;

  float cm[8];
#pragma unroll
  for (int g = 0; g < 8; ++g) cm[g] = -1e30f;

  for (int t = 0; t < NTE; ++t) {
    __syncthreads();  // previous tile's readers done
    stage_tile(nf_hi, cbase, q * ECOLS + t * CT, sh, tid);
    __syncthreads();

#pragma unroll
    for (int p = 0; p < 2; ++p) {
      const int st = wave * 2 + p;
      const ushort_t* ap = sh + (st * 16 + n) * 64;
      const bf16x8 ah0 = *(const bf16x8*)(ap + x0);
      const bf16x8 ah1 = *(const bf16x8*)(ap + x1);
#pragma unroll
      for (int g = 0; g < 8; ++g) {
        f32x4 z = {0.f, 0.f, 0.f, 0.f};
        f32x4 a = __builtin_amdgcn_mfma_f32_16x16x32_bf16(ah0, bh0[g], z, 0, 0, 0);
        a = __builtin_amdgcn_mfma_f32_16x16x32_bf16(ah1, bh1[g], a, 0, 0, 0);
        cm[g] = fmaxf(fmaxf(a[0], a[1]), fmaxf(fmaxf(a[2], a[3]), cm[g]));
      }
    }
  }
  // stream id within row: q*16 + wave*4 + quad  (128 streams x 72 cols)
#pragma unroll
  for (int g = 0; g < 8; ++g)
    tmax[(size_t)(rowbase + g * 16) * NCHUNK + q * 16 + wave * 4 + quad] = cm[g];
}

// ---------------- K2b: threshold = 16th largest of 128 stream maxima - margin ----------------
__global__ __launch_bounds__(256) void k_thresh(
    const float* __restrict__ tmax, float* __restrict__ Tb) {
  const int wave = threadIdx.x >> 6, lane = threadIdx.x & 63;
  const int row = blockIdx.x * 4 + wave;
  const float* tp = tmax + (size_t)row * NCHUNK;
  float v0 = tp[lane];
  float v1 = tp[64 + lane];
  float m = -1e30f;
#pragma unroll
  for (int k = 0; k < TK; ++k) {
    float c = fmaxf(v0, v1);
#pragma unroll
    for (int d = 1; d < 64; d <<= 1) c = fmaxf(c, __shfl_xor(c, d));
    m = c;
    if (v0 == m) v0 = -1e30f;  // killing duplicates only lowers T: safe
    if (v1 == m) v1 = -1e30f;
  }
  if (lane == 0) Tb[row] = m - MARGIN;
}

// ---------------- K2c: pass B — hi sims again, append cols with s_hi >= T ----------------
__global__ __launch_bounds__(256) void k_collect(
    const ushort_t* __restrict__ nf_hi, const float* __restrict__ Tb,
    int* __restrict__ cidx, int* __restrict__ rowcnt) {
  __shared__ ushort_t sh[CT * 64];  // 16 KB
  const int rb = blockIdx.x >> 3, q = blockIdx.x & 7;
  const int tid = threadIdx.x, wave = tid >> 6, lane = tid & 63;
  const int n = lane & 15, quad = lane >> 4;
  const int rowbase = rb * 128 + n;
  const int b = rb >= 72;
  const size_t cbase = (size_t)b * NPIX;

  bf16x8 bh0[8], bh1[8];
  float T[8];
#pragma unroll
  for (int g = 0; g < 8; ++g) {
    const ushort_t* rp = nf_hi + (size_t)(rowbase + g * 16) * 64;
    bh0[g] = *(const bf16x8*)(rp + quad * 8);
    bh1[g] = *(const bf16x8*)(rp + 32 + quad * 8);
    T[g] = Tb[rowbase + g * 16];
  }

  const int x0 = (quad ^ (n & 7)) * 8;
  const int x1 = ((quad + 4) ^ (n & 7)) * 8;

  for (int t = 0; t < NTE; ++t) {
    const int cb = q * ECOLS + t * CT;
    __syncthreads();
    stage_tile(nf_hi, cbase, cb, sh, tid);
    __syncthreads();

#pragma unroll
    for (int p = 0; p < 2; ++p) {
      const int st = wave * 2 + p;
      const ushort_t* ap = sh + (st * 16 + n) * 64;
      const bf16x8 ah0 = *(const bf16x8*)(ap + x0);
      const bf16x8 ah1 = *(const bf16x8*)(ap + x1);
      const int c0 = cb + st * 16 + quad * 4;
#pragma unroll
      for (int g = 0; g < 8; ++g) {
        f32x4 z = {0.f, 0.f, 0.f, 0.f};
        f32x4 a = __builtin_amdgcn_mfma_f32_16x16x32_bf16(ah0, bh0[g], z, 0, 0, 0);
        a = __builtin_amdgcn_mfma_f32_16x16x32_bf16(ah1, bh1[g], a, 0, 0, 0);
        const float Tg = T[g];
        const int m = (a[0] >= Tg) | ((a[1] >= Tg) << 1) |
                      ((a[2] >= Tg) << 2) | ((a[3] >= Tg) << 3);
        if (m) {
          const int rg = rowbase + g * 16;
          int slot = atomicAdd(rowcnt + rg, __popc(m));
#pragma unroll
          for (int r = 0; r < 4; ++r)
            if (m & (1 << r)) {
              if (slot < MAXC) cidx[(size_t)rg * MAXC + slot] = c0 + r;
              ++slot;
            }
        }
      }
    }
  }
}

// ---------------- K3: exact fp32 dots on candidates + top-16 + gather + mean ----------------
// wave per row; grid NROWS/4 = 4608 blocks x 4 waves
__global__ __launch_bounds__(256) void k_merge_gather(
    const float* __restrict__ nf, const int* __restrict__ cidx,
    const int* __restrict__ rowcnt, float* __restrict__ corr) {
  const int wave = threadIdx.x >> 6, lane = threadIdx.x & 63;
  const int row = blockIdx.x * 4 + wave;
  const int b = row >= NPIX;
  const int rl = row - b * NPIX;
  const float* nfb = nf + (size_t)b * NPIX * RC;
  const int C = min(rowcnt[row], MAXC);

  float4 rv[16];
  const float4* r4 = (const float4*)(nf + (size_t)row * RC);
#pragma unroll
  for (int i = 0; i < 16; ++i) rv[i] = r4[i];  // broadcast loads

  const int* cp = cidx + (size_t)row * MAXC;
  unsigned long long k0 = 0, k1 = 0;
  {
    const int c0 = (lane < C) ? cp[lane] : rl;
    const float4* g = (const float4*)(nfb + (size_t)c0 * RC);
    float s = 0.f;
#pragma unroll
    for (int i = 0; i < 16; ++i) {
      float4 a = g[i];
      s += a.x * rv[i].x + a.y * rv[i].y + a.z * rv[i].z + a.w * rv[i].w;
    }
    if (lane < C)
      k0 = ((unsigned long long)ordu(s) << 32) | (uint_t)(~(uint_t)c0);
  }
  if (C > 64) {  // wave-uniform branch, rare
    const int c1 = (64 + lane < C) ? cp[64 + lane] : rl;
    const float4* g = (const float4*)(nfb + (size_t)c1 * RC);
    float s = 0.f;
#pragma unroll
    for (int i = 0; i < 16; ++i) {
      float4 a = g[i];
      s += a.x * rv[i].x + a.y * rv[i].y + a.z * rv[i].z + a.w * rv[i].w;
    }
    if (64 + lane < C)
      k1 = ((unsigned long long)ordu(s) << 32) | (uint_t)(~(uint_t)c1);
  }

  int sel[TK];
#pragma unroll
  for (int t = 0; t < TK; ++t) {
    unsigned long long m = k0 > k1 ? k0 : k1;
#pragma unroll
    for (int d = 1; d < 64; d <<= 1) {
      unsigned long long o = __shfl_xor(m, d);
      m = (o > m) ? o : m;
    }
    sel[t] = (m == 0) ? rl : (int)(~(uint_t)(m & 0xFFFFFFFFull));
    if (k0 == m) k0 = 0;
    else if (k1 == m) k1 = 0;
  }

  float acc = 0.f;
#pragma unroll
  for (int t = 0; t < TK; ++t)
    acc += nfb[(size_t)sel[t] * RC + lane];  // coalesced 256B per t
  corr[(size_t)row * RC + lane] = acc * 0.0625f;
}

// ---------------- K4: proj back to C channels + residual add ----------------
// grid: 72 pixgroups x 8 channel-eighths = 576
__global__ __launch_bounds__(256) void k_proj_add(
    const float* __restrict__ x, const float* __restrict__ wp,
    const float* __restrict__ corr, float* __restrict__ out) {
  const int pg = blockIdx.x >> 3, cq = blockIdx.x & 7;
  const int tid = threadIdx.x;

  __shared__ float wl[32 * RC];  // 8 KB
  {
    const float4* src = (const float4*)(wp + (size_t)cq * 32 * RC);
    float4* dst = (float4*)wl;
#pragma unroll
    for (int i = 0; i < 2; ++i) dst[i * 256 + tid] = src[i * 256 + tid];
  }

  const int p = pg * 256 + tid;
  const int b = p >= NPIX;
  const int n = p - b * NPIX;

  float4 cr[16];
  const float4* c4 = (const float4*)(corr + (size_t)p * RC);
#pragma unroll
  for (int i = 0; i < 16; ++i) cr[i] = c4[i];
  __syncthreads();

  const size_t xb = (size_t)b * NC * NPIX + n;
  for (int cl = 0; cl < 32; ++cl) {
    const float4* w4 = (const float4*)(wl + cl * RC);  // broadcast
    float s = 0.f;
#pragma unroll
    for (int i = 0; i < 16; ++i) {
      float4 w = w4[i];
      s += w.x * cr[i].x + w.y * cr[i].y + w.z * cr[i].z + w.w * cr[i].w;
    }
    const int c = cq * 32 + cl;
    const size_t oi = xb + (size_t)c * NPIX;
    out[oi] = x[oi] + s;  // coalesced
  }
}

extern "C" void kernel_launch(void* const* d_in, const int* in_sizes, int n_in,
                              void* d_out, int out_size, void* d_ws, size_t ws_size,
                              hipStream_t stream) {
  const float* x = (const float*)d_in[0];
  const float* wr = (const float*)d_in[1];
  const float* wp = (const float*)d_in[2];
  float* out = (float*)d_out;

  char* ws = (char*)d_ws;
  // region1 (18,874,368 B) time-shares: feat4 (reduce->normsplit),
  // tmax (sim_max->thresh, 18432*128*4 = 9.4 MB), corr (merge->proj).
  float* feat4 = (float*)ws;
  float* tmax = (float*)ws;
  float* corr = (float*)ws;
  float* nf = (float*)(ws + 18874368);
  ushort_t* nf_hi = (ushort_t*)(ws + 23592960);
  float* Tb = (float*)(ws + 25952256);
  int* rowcnt = (int*)(ws + 26025984);
  int* cidx = (int*)(ws + 26099712);
  // total 35,536,896 B

  hipLaunchKernelGGL(k_reduce, dim3(1152), dim3(256), 0, stream, x, wr, feat4);
  hipLaunchKernelGGL(k_normsplit, dim3(288), dim3(256), 0, stream, feat4, nf, nf_hi);
  hipLaunchKernelGGL(k_sim_max, dim3(1152), dim3(256), 0, stream, nf_hi, tmax);
  hipLaunchKernelGGL(k_thresh, dim3(NROWS / 4), dim3(256), 0, stream, tmax, Tb);
  hipMemsetAsync(rowcnt, 0, NROWS * sizeof(int), stream);
  hipLaunchKernelGGL(k_collect, dim3(1152), dim3(256), 0, stream,
                     nf_hi, Tb, cidx, rowcnt);
  hipLaunchKernelGGL(k_merge_gather, dim3(NROWS / 4), dim3(256), 0, stream,
                     nf, cidx, rowcnt, corr);
  hipLaunchKernelGGL(k_proj_add, dim3(576), dim3(256), 0, stream, x, wp, corr, out);
}

// Round 4
// 279.564 us; speedup vs baseline: 1.3101x; 1.3101x over previous
//
#include <hip/hip_runtime.h>
#include <cstdint>
#include <cstddef>

#define NPIX 9216          // 96*96
#define NB 2
#define NC 256
#define RC 64
#define TK 16
#define NROWS (NB * NPIX)  // 18432
#define CT 128             // cols per LDS tile
#define ECOLS 1152         // cols per eighth
#define NTE 9              // tiles per eighth
#define MAXC 128           // compact candidate slots per row
#define LCAP 128           // per-block per-row LDS candidate capacity (>= MAXC semantics)
#define MARGIN 0.008f      // 2*e, e <= 2.01*2^-9 * ||a||*||b|| = 3.93e-3

typedef unsigned short ushort_t;
typedef unsigned int uint_t;
typedef __bf16 bf16x8 __attribute__((ext_vector_type(8)));
typedef float f32x4 __attribute__((ext_vector_type(4)));

__device__ __forceinline__ uint_t f2bf(float x) {
  uint_t u = __float_as_uint(x);
  return (u + 0x7FFFu + ((u >> 16) & 1u)) >> 16;
}

// monotone float->uint map (bigger float => bigger uint)
__device__ __forceinline__ uint_t ordu(float v) {
  uint_t u = __float_as_uint(v);
  return (u & 0x80000000u) ? ~u : (u | 0x80000000u);
}

// ---------------- K1: 1x1 conv reduce, c-split partials ----------------
// grid: 72 pixgroups x 4 rq x 4 cq = 1152. feat4 layout [rq*4+cq][NROWS][16]
__global__ __launch_bounds__(256) void k_reduce(
    const float* __restrict__ x, const float* __restrict__ wr,
    float* __restrict__ feat4) {
  __shared__ float wl[64 * 16];  // 4 KB: [c_local][r_local]
  const int bi = blockIdx.x;
  const int pg = bi >> 4, rq = (bi >> 2) & 3, cq = bi & 3;
  const int tid = threadIdx.x;
  {
    const int cl = tid >> 2, rg = (tid & 3) * 4;
#pragma unroll
    for (int i = 0; i < 4; ++i)
      wl[cl * 16 + rg + i] = wr[(size_t)(rq * 16 + rg + i) * NC + cq * 64 + cl];
  }
  __syncthreads();

  const int p = pg * 256 + tid;
  const int b = p >= NPIX;
  const int n = p - b * NPIX;
  const float* xp = x + (size_t)b * NC * NPIX + (size_t)cq * 64 * NPIX + n;

  float4 acc[4];
#pragma unroll
  for (int i = 0; i < 4; ++i) acc[i] = make_float4(0.f, 0.f, 0.f, 0.f);

  for (int c = 0; c < 64; ++c) {
    const float xv = xp[(size_t)c * NPIX];           // coalesced
    const float4* w4 = (const float4*)(wl + c * 16); // broadcast
#pragma unroll
    for (int i = 0; i < 4; ++i) {
      float4 w = w4[i];
      acc[i].x += w.x * xv; acc[i].y += w.y * xv;
      acc[i].z += w.z * xv; acc[i].w += w.w * xv;
    }
  }
  float4* o = (float4*)(feat4 + (((size_t)(rq * 4 + cq)) * NROWS + p) * 16);
#pragma unroll
  for (int i = 0; i < 4; ++i) o[i] = acc[i];  // 64B/lane contiguous
}

// ---------------- K1b: sum partials + normalize + bf16 hi ----------------
__global__ __launch_bounds__(256) void k_normsplit(
    const float* __restrict__ feat4, float* __restrict__ nf,
    ushort_t* __restrict__ hi) {
  const int t = blockIdx.x * 256 + threadIdx.x;
  const int p = t >> 2, q = t & 3;  // 4 lanes per pixel
  float4 v[4];
#pragma unroll
  for (int i = 0; i < 4; ++i) v[i] = make_float4(0.f, 0.f, 0.f, 0.f);
#pragma unroll
  for (int pt = 0; pt < 4; ++pt) {
    const float4* fp = (const float4*)(feat4 + (((size_t)(q * 4 + pt)) * NROWS + p) * 16);
#pragma unroll
    for (int i = 0; i < 4; ++i) {
      float4 a = fp[i];
      v[i].x += a.x; v[i].y += a.y; v[i].z += a.z; v[i].w += a.w;
    }
  }
  float ssq = 0.f;
#pragma unroll
  for (int i = 0; i < 4; ++i)
    ssq += v[i].x * v[i].x + v[i].y * v[i].y + v[i].z * v[i].z + v[i].w * v[i].w;
  ssq += __shfl_xor(ssq, 1);
  ssq += __shfl_xor(ssq, 2);
  const float inv = 1.f / fmaxf(sqrtf(ssq), 1e-12f);

  float s[16];
#pragma unroll
  for (int i = 0; i < 4; ++i) {
    s[i * 4 + 0] = v[i].x * inv; s[i * 4 + 1] = v[i].y * inv;
    s[i * 4 + 2] = v[i].z * inv; s[i * 4 + 3] = v[i].w * inv;
  }
  float4* no = (float4*)(nf + (size_t)p * RC + q * 16);
#pragma unroll
  for (int i = 0; i < 4; ++i)
    no[i] = make_float4(s[i * 4], s[i * 4 + 1], s[i * 4 + 2], s[i * 4 + 3]);

  uint_t hs[16];
#pragma unroll
  for (int i = 0; i < 16; ++i) hs[i] = f2bf(s[i]);
  uint4* ho = (uint4*)(hi + (size_t)p * RC + q * 16);
#pragma unroll
  for (int h = 0; h < 2; ++h)
    ho[h] = make_uint4(hs[h*8+0] | (hs[h*8+1] << 16), hs[h*8+2] | (hs[h*8+3] << 16),
                       hs[h*8+4] | (hs[h*8+5] << 16), hs[h*8+6] | (hs[h*8+7] << 16));
}

// ---------------- K2a: pass A — hi sims, per-lane chunk maxima ----------------
// grid: 144 rowblocks(128 rows) x 8 col-eighths = 1152   (r0-verbatim)
__global__ __launch_bounds__(256) void k_sim_max(
    const ushort_t* __restrict__ nf_hi, float* __restrict__ tmax) {
  __shared__ ushort_t sh[CT * 72];
  const int rb = blockIdx.x >> 3, q = blockIdx.x & 7;
  const int tid = threadIdx.x, wave = tid >> 6, lane = tid & 63;
  const int n = lane & 15, quad = lane >> 4;
  const int r0 = rb * 128 + wave * 32 + n, r1 = r0 + 16;
  const int b = rb >= 72;
  const size_t cbase = (size_t)b * NPIX;

  const bf16x8 bh00 = *(const bf16x8*)(nf_hi + (size_t)r0 * 64 + quad * 8);
  const bf16x8 bh01 = *(const bf16x8*)(nf_hi + (size_t)r0 * 64 + 32 + quad * 8);
  const bf16x8 bh10 = *(const bf16x8*)(nf_hi + (size_t)r1 * 64 + quad * 8);
  const bf16x8 bh11 = *(const bf16x8*)(nf_hi + (size_t)r1 * 64 + 32 + quad * 8);

  const int sc = tid >> 1, sseg = (tid & 1) * 32;
  float cm0 = -1e30f, cm1 = -1e30f;

  for (int t = 0; t < NTE; ++t) {
    const int cb = q * ECOLS + t * CT;
    __syncthreads();
    {
      const uint4* g = (const uint4*)(nf_hi + (cbase + cb + sc) * 64 + sseg);
      uint4* d = (uint4*)(sh + sc * 72 + sseg);
#pragma unroll
      for (int i = 0; i < 4; ++i) d[i] = g[i];
    }
    __syncthreads();

#pragma unroll 2
    for (int st = 0; st < 8; ++st) {
      const ushort_t* ap = sh + (st * 16 + n) * 72 + quad * 8;
      bf16x8 ah0 = *(const bf16x8*)ap;
      bf16x8 ah1 = *(const bf16x8*)(ap + 32);
      f32x4 z = {0.f, 0.f, 0.f, 0.f};
      f32x4 a0 = __builtin_amdgcn_mfma_f32_16x16x32_bf16(ah0, bh00, z, 0, 0, 0);
      a0 = __builtin_amdgcn_mfma_f32_16x16x32_bf16(ah1, bh01, a0, 0, 0, 0);
      f32x4 a1 = __builtin_amdgcn_mfma_f32_16x16x32_bf16(ah0, bh10, z, 0, 0, 0);
      a1 = __builtin_amdgcn_mfma_f32_16x16x32_bf16(ah1, bh11, a1, 0, 0, 0);
      cm0 = fmaxf(cm0, fmaxf(fmaxf(a0[0], a0[1]), fmaxf(a0[2], a0[3])));
      cm1 = fmaxf(cm1, fmaxf(fmaxf(a1[0], a1[1]), fmaxf(a1[2], a1[3])));
    }
    if (t % 3 == 2) {  // 3 tiles = 96 cols per lane-stream chunk
      const int cn = t / 3;
      tmax[(size_t)r0 * 96 + (q * 4 + quad) * 3 + cn] = cm0;
      tmax[(size_t)r1 * 96 + (q * 4 + quad) * 3 + cn] = cm1;
      cm0 = -1e30f; cm1 = -1e30f;
    }
  }
}

// ---------------- K2b: threshold = 16th largest of 96 chunk maxima - margin ----------------
__global__ __launch_bounds__(256) void k_thresh(
    const float* __restrict__ tmax, float* __restrict__ Tb) {
  const int wave = threadIdx.x >> 6, lane = threadIdx.x & 63;
  const int row = blockIdx.x * 4 + wave;
  const float* tp = tmax + (size_t)row * 96;
  float v0 = tp[lane];
  float v1 = (lane < 32) ? tp[64 + lane] : -1e30f;
  float m = -1e30f;
#pragma unroll
  for (int k = 0; k < TK; ++k) {
    float c = fmaxf(v0, v1);
#pragma unroll
    for (int d = 1; d < 64; d <<= 1) c = fmaxf(c, __shfl_xor(c, d));
    m = c;
    if (v0 == m) v0 = -1e30f;  // killing duplicates only lowers T: safe
    if (v1 == m) v1 = -1e30f;
  }
  if (lane == 0) Tb[row] = m - MARGIN;
}

// ---------------- K2c: pass B — hi sims again, collect cols with s_hi >= T ----------------
// r0 structure, but candidates go to per-row LDS lists (block-local atomics);
// ONE global atomicAdd per row per block at flush (32 in parallel per wave).
__global__ __launch_bounds__(256) void k_collect(
    const ushort_t* __restrict__ nf_hi, const float* __restrict__ Tb,
    int* __restrict__ cidx, int* __restrict__ rowcnt) {
  __shared__ ushort_t sh[CT * 72];          // 18 KB staging (r0 layout)
  __shared__ ushort_t lst[128][LCAP + 1];   // 33 KB per-row candidate lists (+1 anti-bank-conflict)
  __shared__ int lcnt[128];                 // 512 B
  const int rb = blockIdx.x >> 3, q = blockIdx.x & 7;
  const int tid = threadIdx.x, wave = tid >> 6, lane = tid & 63;
  const int n = lane & 15, quad = lane >> 4;
  const int rl0 = wave * 32 + n, rl1 = rl0 + 16;  // row-local ids in [0,128)
  const int r0 = rb * 128 + rl0, r1 = r0 + 16;
  const int b = rb >= 72;
  const size_t cbase = (size_t)b * NPIX;

  if (tid < 128) lcnt[tid] = 0;

  const bf16x8 bh00 = *(const bf16x8*)(nf_hi + (size_t)r0 * 64 + quad * 8);
  const bf16x8 bh01 = *(const bf16x8*)(nf_hi + (size_t)r0 * 64 + 32 + quad * 8);
  const bf16x8 bh10 = *(const bf16x8*)(nf_hi + (size_t)r1 * 64 + quad * 8);
  const bf16x8 bh11 = *(const bf16x8*)(nf_hi + (size_t)r1 * 64 + 32 + quad * 8);

  const float T0 = Tb[r0], T1 = Tb[r1];
  const int sc = tid >> 1, sseg = (tid & 1) * 32;

  for (int t = 0; t < NTE; ++t) {
    const int cb = q * ECOLS + t * CT;
    __syncthreads();
    {
      const uint4* g = (const uint4*)(nf_hi + (cbase + cb + sc) * 64 + sseg);
      uint4* d = (uint4*)(sh + sc * 72 + sseg);
#pragma unroll
      for (int i = 0; i < 4; ++i) d[i] = g[i];
    }
    __syncthreads();

#pragma unroll 2
    for (int st = 0; st < 8; ++st) {
      const ushort_t* ap = sh + (st * 16 + n) * 72 + quad * 8;
      bf16x8 ah0 = *(const bf16x8*)ap;
      bf16x8 ah1 = *(const bf16x8*)(ap + 32);
      f32x4 z = {0.f, 0.f, 0.f, 0.f};
      f32x4 a0 = __builtin_amdgcn_mfma_f32_16x16x32_bf16(ah0, bh00, z, 0, 0, 0);
      a0 = __builtin_amdgcn_mfma_f32_16x16x32_bf16(ah1, bh01, a0, 0, 0, 0);
      f32x4 a1 = __builtin_amdgcn_mfma_f32_16x16x32_bf16(ah0, bh10, z, 0, 0, 0);
      a1 = __builtin_amdgcn_mfma_f32_16x16x32_bf16(ah1, bh11, a1, 0, 0, 0);

      const int c0 = cb + st * 16 + quad * 4;
      const int m0 = (a0[0] >= T0) | ((a0[1] >= T0) << 1) |
                     ((a0[2] >= T0) << 2) | ((a0[3] >= T0) << 3);
      if (m0) {
        int slot = atomicAdd(&lcnt[rl0], __popc(m0));  // LDS atomic, block-local
#pragma unroll
        for (int r = 0; r < 4; ++r)
          if (m0 & (1 << r)) {
            if (slot < LCAP) lst[rl0][slot] = (ushort_t)(c0 + r);
            ++slot;
          }
      }
      const int m1 = (a1[0] >= T1) | ((a1[1] >= T1) << 1) |
                     ((a1[2] >= T1) << 2) | ((a1[3] >= T1) << 3);
      if (m1) {
        int slot = atomicAdd(&lcnt[rl1], __popc(m1));
#pragma unroll
        for (int r = 0; r < 4; ++r)
          if (m1 & (1 << r)) {
            if (slot < LCAP) lst[rl1][slot] = (ushort_t)(c0 + r);
            ++slot;
          }
      }
    }
  }
  __syncthreads();
  // flush: one global reservation per row, 128 rows by threads 0..127 (parallel atomics)
  if (tid < 128) {
    const int row = rb * 128 + tid;
    const int cnt = min(lcnt[tid], LCAP);
    int base = atomicAdd(rowcnt + row, cnt);
    for (int j = 0; j < cnt; ++j) {
      const int gs = base + j;
      if (gs < MAXC) cidx[(size_t)row * MAXC + gs] = (int)lst[tid][j];
    }
  }
}

// ---------------- K3: exact fp32 dots on candidates + top-16 + gather + mean ----------------
// wave per row; grid NROWS/4 = 4608 blocks x 4 waves.
// top-16 via 64-bit ballot-bisection (keys distinct => exactly 16 selected).
__global__ __launch_bounds__(256) void k_merge_gather(
    const float* __restrict__ nf, const int* __restrict__ cidx,
    const int* __restrict__ rowcnt, float* __restrict__ corr) {
  __shared__ ushort_t selc[4][TK];
  const int wave = threadIdx.x >> 6, lane = threadIdx.x & 63;
  const int row = blockIdx.x * 4 + wave;
  const int b = row >= NPIX;
  const int rl = row - b * NPIX;
  const float* nfb = nf + (size_t)b * NPIX * RC;
  const int C = min(rowcnt[row], MAXC);

  if (lane < TK) selc[wave][lane] = (ushort_t)rl;  // safety pad (C<16 impossible by construction)
  __syncthreads();

  float4 rv[16];
  const float4* r4 = (const float4*)(nf + (size_t)row * RC);
#pragma unroll
  for (int i = 0; i < 16; ++i) rv[i] = r4[i];  // broadcast loads

  const int* cp = cidx + (size_t)row * MAXC;
  unsigned long long k0 = 0, k1 = 0;
  int c0 = rl, c1 = rl;
  {
    c0 = (lane < C) ? cp[lane] : rl;
    const float4* g = (const float4*)(nfb + (size_t)c0 * RC);
    float s = 0.f;
#pragma unroll
    for (int i = 0; i < 16; ++i) {
      float4 a = g[i];
      s += a.x * rv[i].x + a.y * rv[i].y + a.z * rv[i].z + a.w * rv[i].w;
    }
    if (lane < C)
      k0 = ((unsigned long long)ordu(s) << 32) | (uint_t)(~(uint_t)c0);
  }
  if (C > 64) {  // wave-uniform branch, rare
    c1 = (64 + lane < C) ? cp[64 + lane] : rl;
    const float4* g = (const float4*)(nfb + (size_t)c1 * RC);
    float s = 0.f;
#pragma unroll
    for (int i = 0; i < 16; ++i) {
      float4 a = g[i];
      s += a.x * rv[i].x + a.y * rv[i].y + a.z * rv[i].z + a.w * rv[i].w;
    }
    if (64 + lane < C)
      k1 = ((unsigned long long)ordu(s) << 32) | (uint_t)(~(uint_t)c1);
  }

  // bisection: largest thr with |{keys >= thr}| >= 16; distinct keys => exactly 16
  unsigned long long thr = 0;
#pragma unroll
  for (int bit = 63; bit >= 0; --bit) {
    const unsigned long long cand = thr | (1ull << bit);
    const int cnt = __popcll(__ballot(k0 >= cand)) + __popcll(__ballot(k1 >= cand));
    if (cnt >= TK) thr = cand;
  }
  if (thr != 0) {  // thr==0 only if <16 keys total (impossible; pad stays)
    const unsigned long long ml = (lane == 0) ? 0ull : (~0ull >> (64 - lane));
    const unsigned long long b0 = __ballot(k0 >= thr);
    const unsigned long long b1 = __ballot(k1 >= thr);
    const int n0 = __popcll(b0);
    if (k0 >= thr) {
      const int r = __popcll(b0 & ml);
      if (r < TK) selc[wave][r] = (ushort_t)c0;
    }
    if (k1 >= thr) {
      const int r = n0 + __popcll(b1 & ml);
      if (r < TK) selc[wave][r] = (ushort_t)c1;
    }
  }
  __syncthreads();

  float acc = 0.f;
#pragma unroll
  for (int t = 0; t < TK; ++t)
    acc += nfb[(size_t)selc[wave][t] * RC + lane];  // coalesced 256B per t
  corr[(size_t)row * RC + lane] = acc * 0.0625f;
}

// ---------------- K4: proj back to C channels + residual add ----------------
// grid: 72 pixgroups x 8 channel-eighths = 576
__global__ __launch_bounds__(256) void k_proj_add(
    const float* __restrict__ x, const float* __restrict__ wp,
    const float* __restrict__ corr, float* __restrict__ out) {
  const int pg = blockIdx.x >> 3, cq = blockIdx.x & 7;
  const int tid = threadIdx.x;

  __shared__ float wl[32 * RC];  // 8 KB
  {
    const float4* src = (const float4*)(wp + (size_t)cq * 32 * RC);
    float4* dst = (float4*)wl;
#pragma unroll
    for (int i = 0; i < 2; ++i) dst[i * 256 + tid] = src[i * 256 + tid];
  }

  const int p = pg * 256 + tid;
  const int b = p >= NPIX;
  const int n = p - b * NPIX;

  float4 cr[16];
  const float4* c4 = (const float4*)(corr + (size_t)p * RC);
#pragma unroll
  for (int i = 0; i < 16; ++i) cr[i] = c4[i];
  __syncthreads();

  const size_t xb = (size_t)b * NC * NPIX + n;
  for (int cl = 0; cl < 32; ++cl) {
    const float4* w4 = (const float4*)(wl + cl * RC);  // broadcast
    float s = 0.f;
#pragma unroll
    for (int i = 0; i < 16; ++i) {
      float4 w = w4[i];
      s += w.x * cr[i].x + w.y * cr[i].y + w.z * cr[i].z + w.w * cr[i].w;
    }
    const int c = cq * 32 + cl;
    const size_t oi = xb + (size_t)c * NPIX;
    out[oi] = x[oi] + s;  // coalesced
  }
}

extern "C" void kernel_launch(void* const* d_in, const int* in_sizes, int n_in,
                              void* d_out, int out_size, void* d_ws, size_t ws_size,
                              hipStream_t stream) {
  const float* x = (const float*)d_in[0];
  const float* wr = (const float*)d_in[1];
  const float* wp = (const float*)d_in[2];
  float* out = (float*)d_out;

  char* ws = (char*)d_ws;
  // region1 (18,874,368 B) time-shares: feat4 (reduce->normsplit),
  // tmax (sim_max->thresh), corr (merge->proj) — lifetimes disjoint.
  float* feat4 = (float*)ws;
  float* tmax = (float*)ws;
  float* corr = (float*)ws;
  float* nf = (float*)(ws + 18874368);
  ushort_t* nf_hi = (ushort_t*)(ws + 23592960);
  float* Tb = (float*)(ws + 25952256);
  int* rowcnt = (int*)(ws + 26025984);
  int* cidx = (int*)(ws + 26099712);
  // total 35,536,896 B

  hipLaunchKernelGGL(k_reduce, dim3(1152), dim3(256), 0, stream, x, wr, feat4);
  hipLaunchKernelGGL(k_normsplit, dim3(288), dim3(256), 0, stream, feat4, nf, nf_hi);
  hipLaunchKernelGGL(k_sim_max, dim3(1152), dim3(256), 0, stream, nf_hi, tmax);
  hipLaunchKernelGGL(k_thresh, dim3(NROWS / 4), dim3(256), 0, stream, tmax, Tb);
  hipMemsetAsync(rowcnt, 0, NROWS * sizeof(int), stream);
  hipLaunchKernelGGL(k_collect, dim3(1152), dim3(256), 0, stream,
                     nf_hi, Tb, cidx, rowcnt);
  hipLaunchKernelGGL(k_merge_gather, dim3(NROWS / 4), dim3(256), 0, stream,
                     nf, cidx, rowcnt, corr);
  hipLaunchKernelGGL(k_proj_add, dim3(576), dim3(256), 0, stream, x, wp, corr, out);
}

// Round 5
// 273.784 us; speedup vs baseline: 1.3378x; 1.0211x over previous
//
#include <hip/hip_runtime.h>
#include <cstdint>
#include <cstddef>

#define NPIX 9216          // 96*96
#define NB 2
#define NC 256
#define RC 64
#define TK 16
#define NROWS (NB * NPIX)  // 18432
#define CT 128             // cols per LDS tile
#define ECOLS 1152         // cols per eighth
#define NTE 9              // tiles per eighth
#define MAXC 128           // compact candidate slots per row
#define LCAP 64            // per-block per-row LDS candidate capacity
#define MARGIN 0.008f      // 2*e, e <= 2.01*2^-9 * ||a||*||b|| = 3.93e-3

typedef unsigned short ushort_t;
typedef unsigned int uint_t;
typedef __bf16 bf16x8 __attribute__((ext_vector_type(8)));
typedef float f32x4 __attribute__((ext_vector_type(4)));

__device__ __forceinline__ uint_t f2bf(float x) {
  uint_t u = __float_as_uint(x);
  return (u + 0x7FFFu + ((u >> 16) & 1u)) >> 16;
}

// monotone float->uint map (bigger float => bigger uint)
__device__ __forceinline__ uint_t ordu(float v) {
  uint_t u = __float_as_uint(v);
  return (u & 0x80000000u) ? ~u : (u | 0x80000000u);
}

// async global->LDS, 16B per lane. dest is wave-uniform base (HW adds lane*16).
#define GL2LDS(gsrc, ldst)                                                   \
  __builtin_amdgcn_global_load_lds(                                          \
      (const __attribute__((address_space(1))) uint_t*)(const void*)(gsrc),  \
      (__attribute__((address_space(3))) uint_t*)(void*)(ldst), 16, 0, 0)

// Stage one 128x64 bf16 tile (16 KB) via global_load_lds.
// LDS is linear [128][64]; source is pre-swizzled so that physical 16B-slot s
// of row r holds global slot s^(r&7) (rule #21: linear dest + swizzled source;
// layout identical to r2 where it measured 0 bank conflicts and passed).
__device__ __forceinline__ void stage_tile(
    const ushort_t* __restrict__ nf_hi, size_t cbase, int cb,
    ushort_t* shbuf, int tid) {
  const int wave = tid >> 6, l = tid & 63;
  const int lr = l >> 3;             // row within 8-row group
  const int ls = (l & 7) ^ lr;       // swizzled global slot
#pragma unroll
  for (int i = 0; i < 4; ++i) {
    const int j = wave * 4 + i;      // instruction covers rows 8j..8j+7
    const ushort_t* g = nf_hi + (cbase + (size_t)(cb + j * 8 + lr)) * 64 + ls * 8;
    ushort_t* d = shbuf + j * 512;   // 1024 B per instruction, wave-uniform
    GL2LDS(g, d);
  }
}

// ---------------- K1: 1x1 conv reduce, c-split partials ----------------
// grid: 72 pixgroups x 4 rq x 4 cq = 1152. feat4 layout [rq*4+cq][NROWS][16]
__global__ __launch_bounds__(256) void k_reduce(
    const float* __restrict__ x, const float* __restrict__ wr,
    float* __restrict__ feat4) {
  __shared__ float wl[64 * 16];  // 4 KB: [c_local][r_local]
  const int bi = blockIdx.x;
  const int pg = bi >> 4, rq = (bi >> 2) & 3, cq = bi & 3;
  const int tid = threadIdx.x;
  {
    const int cl = tid >> 2, rg = (tid & 3) * 4;
#pragma unroll
    for (int i = 0; i < 4; ++i)
      wl[cl * 16 + rg + i] = wr[(size_t)(rq * 16 + rg + i) * NC + cq * 64 + cl];
  }
  __syncthreads();

  const int p = pg * 256 + tid;
  const int b = p >= NPIX;
  const int n = p - b * NPIX;
  const float* xp = x + (size_t)b * NC * NPIX + (size_t)cq * 64 * NPIX + n;

  float4 acc[4];
#pragma unroll
  for (int i = 0; i < 4; ++i) acc[i] = make_float4(0.f, 0.f, 0.f, 0.f);

  for (int c = 0; c < 64; ++c) {
    const float xv = xp[(size_t)c * NPIX];           // coalesced
    const float4* w4 = (const float4*)(wl + c * 16); // broadcast
#pragma unroll
    for (int i = 0; i < 4; ++i) {
      float4 w = w4[i];
      acc[i].x += w.x * xv; acc[i].y += w.y * xv;
      acc[i].z += w.z * xv; acc[i].w += w.w * xv;
    }
  }
  float4* o = (float4*)(feat4 + (((size_t)(rq * 4 + cq)) * NROWS + p) * 16);
#pragma unroll
  for (int i = 0; i < 4; ++i) o[i] = acc[i];  // 64B/lane contiguous
}

// ---------------- K1b: sum partials + normalize + bf16 hi ----------------
__global__ __launch_bounds__(256) void k_normsplit(
    const float* __restrict__ feat4, float* __restrict__ nf,
    ushort_t* __restrict__ hi) {
  const int t = blockIdx.x * 256 + threadIdx.x;
  const int p = t >> 2, q = t & 3;  // 4 lanes per pixel
  float4 v[4];
#pragma unroll
  for (int i = 0; i < 4; ++i) v[i] = make_float4(0.f, 0.f, 0.f, 0.f);
#pragma unroll
  for (int pt = 0; pt < 4; ++pt) {
    const float4* fp = (const float4*)(feat4 + (((size_t)(q * 4 + pt)) * NROWS + p) * 16);
#pragma unroll
    for (int i = 0; i < 4; ++i) {
      float4 a = fp[i];
      v[i].x += a.x; v[i].y += a.y; v[i].z += a.z; v[i].w += a.w;
    }
  }
  float ssq = 0.f;
#pragma unroll
  for (int i = 0; i < 4; ++i)
    ssq += v[i].x * v[i].x + v[i].y * v[i].y + v[i].z * v[i].z + v[i].w * v[i].w;
  ssq += __shfl_xor(ssq, 1);
  ssq += __shfl_xor(ssq, 2);
  const float inv = 1.f / fmaxf(sqrtf(ssq), 1e-12f);

  float s[16];
#pragma unroll
  for (int i = 0; i < 4; ++i) {
    s[i * 4 + 0] = v[i].x * inv; s[i * 4 + 1] = v[i].y * inv;
    s[i * 4 + 2] = v[i].z * inv; s[i * 4 + 3] = v[i].w * inv;
  }
  float4* no = (float4*)(nf + (size_t)p * RC + q * 16);
#pragma unroll
  for (int i = 0; i < 4; ++i)
    no[i] = make_float4(s[i * 4], s[i * 4 + 1], s[i * 4 + 2], s[i * 4 + 3]);

  uint_t hs[16];
#pragma unroll
  for (int i = 0; i < 16; ++i) hs[i] = f2bf(s[i]);
  uint4* ho = (uint4*)(hi + (size_t)p * RC + q * 16);
#pragma unroll
  for (int h = 0; h < 2; ++h)
    ho[h] = make_uint4(hs[h*8+0] | (hs[h*8+1] << 16), hs[h*8+2] | (hs[h*8+3] << 16),
                       hs[h*8+4] | (hs[h*8+5] << 16), hs[h*8+6] | (hs[h*8+7] << 16));
}

// ---------------- K2a: pass A — hi sims, per-lane chunk maxima ----------------
// grid: 144 rowblocks(128 rows) x 8 col-eighths = 1152.
// Single-buffer global_load_lds staging: stage -> barrier(vmcnt drain) ->
// full-unrolled compute (ds_read offsets fold to immediates) -> barrier.
__global__ __launch_bounds__(256) void k_sim_max(
    const ushort_t* __restrict__ nf_hi, float* __restrict__ tmax) {
  __shared__ ushort_t sh[CT * 64];  // 16 KB linear
  const int rb = blockIdx.x >> 3, q = blockIdx.x & 7;
  const int tid = threadIdx.x, wave = tid >> 6, lane = tid & 63;
  const int n = lane & 15, quad = lane >> 4;
  const int r0 = rb * 128 + wave * 32 + n, r1 = r0 + 16;
  const int b = rb >= 72;
  const size_t cbase = (size_t)b * NPIX;
  const int x0 = (quad ^ (n & 7)) * 8;        // swizzled slot offsets (ushorts)
  const int x1 = ((quad + 4) ^ (n & 7)) * 8;

  const bf16x8 bh00 = *(const bf16x8*)(nf_hi + (size_t)r0 * 64 + quad * 8);
  const bf16x8 bh01 = *(const bf16x8*)(nf_hi + (size_t)r0 * 64 + 32 + quad * 8);
  const bf16x8 bh10 = *(const bf16x8*)(nf_hi + (size_t)r1 * 64 + quad * 8);
  const bf16x8 bh11 = *(const bf16x8*)(nf_hi + (size_t)r1 * 64 + 32 + quad * 8);

  float cm0 = -1e30f, cm1 = -1e30f;

  for (int t = 0; t < NTE; ++t) {
    stage_tile(nf_hi, cbase, q * ECOLS + t * CT, sh, tid);
    __syncthreads();  // drains vmcnt(0): tile resident

#pragma unroll
    for (int st = 0; st < 8; ++st) {
      const ushort_t* ap = sh + (st * 16 + n) * 64;
      bf16x8 ah0 = *(const bf16x8*)(ap + x0);
      bf16x8 ah1 = *(const bf16x8*)(ap + x1);
      f32x4 z = {0.f, 0.f, 0.f, 0.f};
      f32x4 a0 = __builtin_amdgcn_mfma_f32_16x16x32_bf16(ah0, bh00, z, 0, 0, 0);
      a0 = __builtin_amdgcn_mfma_f32_16x16x32_bf16(ah1, bh01, a0, 0, 0, 0);
      f32x4 a1 = __builtin_amdgcn_mfma_f32_16x16x32_bf16(ah0, bh10, z, 0, 0, 0);
      a1 = __builtin_amdgcn_mfma_f32_16x16x32_bf16(ah1, bh11, a1, 0, 0, 0);
      cm0 = fmaxf(fmaxf(a0[0], a0[1]), fmaxf(fmaxf(a0[2], a0[3]), cm0));
      cm1 = fmaxf(fmaxf(a1[0], a1[1]), fmaxf(fmaxf(a1[2], a1[3]), cm1));
    }
    if (t % 3 == 2) {  // 3 tiles = 96 cols per lane-stream chunk
      const int cn = t / 3;
      tmax[(size_t)r0 * 96 + (q * 4 + quad) * 3 + cn] = cm0;
      tmax[(size_t)r1 * 96 + (q * 4 + quad) * 3 + cn] = cm1;
      cm0 = -1e30f; cm1 = -1e30f;
    }
    __syncthreads();  // readers done before next stage overwrites
  }
}

// ---------------- K2b: threshold = 16th largest of 96 chunk maxima - margin ----------------
__global__ __launch_bounds__(256) void k_thresh(
    const float* __restrict__ tmax, float* __restrict__ Tb) {
  const int wave = threadIdx.x >> 6, lane = threadIdx.x & 63;
  const int row = blockIdx.x * 4 + wave;
  const float* tp = tmax + (size_t)row * 96;
  float v0 = tp[lane];
  float v1 = (lane < 32) ? tp[64 + lane] : -1e30f;
  float m = -1e30f;
#pragma unroll
  for (int k = 0; k < TK; ++k) {
    float c = fmaxf(v0, v1);
#pragma unroll
    for (int d = 1; d < 64; d <<= 1) c = fmaxf(c, __shfl_xor(c, d));
    m = c;
    if (v0 == m) v0 = -1e30f;  // killing duplicates only lowers T: safe
    if (v1 == m) v1 = -1e30f;
  }
  if (lane == 0) Tb[row] = m - MARGIN;
}

// ---------------- K2c: pass B — hi sims again, collect cols with s_hi >= T ----------------
// Candidates go to per-row LDS lists (block-local atomics); ONE global
// atomicAdd per row per block at flush.
__global__ __launch_bounds__(256) void k_collect(
    const ushort_t* __restrict__ nf_hi, const float* __restrict__ Tb,
    int* __restrict__ cidx, int* __restrict__ rowcnt) {
  __shared__ ushort_t sh[CT * 64];          // 16 KB staging (linear, swizzled source)
  __shared__ ushort_t lst[128][LCAP + 1];   // 16.6 KB per-row candidate lists
  __shared__ int lcnt[128];                 // 512 B
  const int rb = blockIdx.x >> 3, q = blockIdx.x & 7;
  const int tid = threadIdx.x, wave = tid >> 6, lane = tid & 63;
  const int n = lane & 15, quad = lane >> 4;
  const int rl0 = wave * 32 + n, rl1 = rl0 + 16;  // row-local ids in [0,128)
  const int r0 = rb * 128 + rl0, r1 = r0 + 16;
  const int b = rb >= 72;
  const size_t cbase = (size_t)b * NPIX;
  const int x0 = (quad ^ (n & 7)) * 8;
  const int x1 = ((quad + 4) ^ (n & 7)) * 8;

  if (tid < 128) lcnt[tid] = 0;

  const bf16x8 bh00 = *(const bf16x8*)(nf_hi + (size_t)r0 * 64 + quad * 8);
  const bf16x8 bh01 = *(const bf16x8*)(nf_hi + (size_t)r0 * 64 + 32 + quad * 8);
  const bf16x8 bh10 = *(const bf16x8*)(nf_hi + (size_t)r1 * 64 + quad * 8);
  const bf16x8 bh11 = *(const bf16x8*)(nf_hi + (size_t)r1 * 64 + 32 + quad * 8);

  const float T0 = Tb[r0], T1 = Tb[r1];

  for (int t = 0; t < NTE; ++t) {
    const int cb = q * ECOLS + t * CT;
    stage_tile(nf_hi, cbase, cb, sh, tid);
    __syncthreads();  // vmcnt drained: tile resident (also covers lcnt init)

#pragma unroll
    for (int st = 0; st < 8; ++st) {
      const ushort_t* ap = sh + (st * 16 + n) * 64;
      bf16x8 ah0 = *(const bf16x8*)(ap + x0);
      bf16x8 ah1 = *(const bf16x8*)(ap + x1);
      f32x4 z = {0.f, 0.f, 0.f, 0.f};
      f32x4 a0 = __builtin_amdgcn_mfma_f32_16x16x32_bf16(ah0, bh00, z, 0, 0, 0);
      a0 = __builtin_amdgcn_mfma_f32_16x16x32_bf16(ah1, bh01, a0, 0, 0, 0);
      f32x4 a1 = __builtin_amdgcn_mfma_f32_16x16x32_bf16(ah0, bh10, z, 0, 0, 0);
      a1 = __builtin_amdgcn_mfma_f32_16x16x32_bf16(ah1, bh11, a1, 0, 0, 0);

      const int c0 = cb + st * 16 + quad * 4;
      const int m0 = (a0[0] >= T0) | ((a0[1] >= T0) << 1) |
                     ((a0[2] >= T0) << 2) | ((a0[3] >= T0) << 3);
      if (m0) {
        int slot = atomicAdd(&lcnt[rl0], __popc(m0));  // LDS atomic, block-local
#pragma unroll
        for (int r = 0; r < 4; ++r)
          if (m0 & (1 << r)) {
            if (slot < LCAP) lst[rl0][slot] = (ushort_t)(c0 + r);
            ++slot;
          }
      }
      const int m1 = (a1[0] >= T1) | ((a1[1] >= T1) << 1) |
                     ((a1[2] >= T1) << 2) | ((a1[3] >= T1) << 3);
      if (m1) {
        int slot = atomicAdd(&lcnt[rl1], __popc(m1));
#pragma unroll
        for (int r = 0; r < 4; ++r)
          if (m1 & (1 << r)) {
            if (slot < LCAP) lst[rl1][slot] = (ushort_t)(c0 + r);
            ++slot;
          }
      }
    }
    __syncthreads();  // readers done before next stage overwrites
  }
  // flush: one global reservation per row, 128 rows by threads 0..127 (parallel atomics)
  if (tid < 128) {
    const int row = rb * 128 + tid;
    const int cnt = min(lcnt[tid], LCAP);
    int base = atomicAdd(rowcnt + row, cnt);
    for (int j = 0; j < cnt; ++j) {
      const int gs = base + j;
      if (gs < MAXC) cidx[(size_t)row * MAXC + gs] = (int)lst[tid][j];
    }
  }
}

// ---------------- K3: exact fp32 dots on candidates + top-16 + gather + mean ----------------
// wave per row; grid NROWS/4 = 4608 blocks x 4 waves.
// top-16 via 64-bit ballot-bisection (keys distinct => exactly 16 selected).
__global__ __launch_bounds__(256) void k_merge_gather(
    const float* __restrict__ nf, const int* __restrict__ cidx,
    const int* __restrict__ rowcnt, float* __restrict__ corr) {
  __shared__ ushort_t selc[4][TK];
  const int wave = threadIdx.x >> 6, lane = threadIdx.x & 63;
  const int row = blockIdx.x * 4 + wave;
  const int b = row >= NPIX;
  const int rl = row - b * NPIX;
  const float* nfb = nf + (size_t)b * NPIX * RC;
  const int C = min(rowcnt[row], MAXC);

  if (lane < TK) selc[wave][lane] = (ushort_t)rl;  // safety pad (C<16 impossible by construction)
  __syncthreads();

  float4 rv[16];
  const float4* r4 = (const float4*)(nf + (size_t)row * RC);
#pragma unroll
  for (int i = 0; i < 16; ++i) rv[i] = r4[i];  // broadcast loads

  const int* cp = cidx + (size_t)row * MAXC;
  unsigned long long k0 = 0, k1 = 0;
  int c0 = rl, c1 = rl;
  {
    c0 = (lane < C) ? cp[lane] : rl;
    const float4* g = (const float4*)(nfb + (size_t)c0 * RC);
    float s = 0.f;
#pragma unroll
    for (int i = 0; i < 16; ++i) {
      float4 a = g[i];
      s += a.x * rv[i].x + a.y * rv[i].y + a.z * rv[i].z + a.w * rv[i].w;
    }
    if (lane < C)
      k0 = ((unsigned long long)ordu(s) << 32) | (uint_t)(~(uint_t)c0);
  }
  if (C > 64) {  // wave-uniform branch, rare
    c1 = (64 + lane < C) ? cp[64 + lane] : rl;
    const float4* g = (const float4*)(nfb + (size_t)c1 * RC);
    float s = 0.f;
#pragma unroll
    for (int i = 0; i < 16; ++i) {
      float4 a = g[i];
      s += a.x * rv[i].x + a.y * rv[i].y + a.z * rv[i].z + a.w * rv[i].w;
    }
    if (64 + lane < C)
      k1 = ((unsigned long long)ordu(s) << 32) | (uint_t)(~(uint_t)c1);
  }

  // bisection: largest thr with |{keys >= thr}| >= 16; distinct keys => exactly 16
  unsigned long long thr = 0;
#pragma unroll
  for (int bit = 63; bit >= 0; --bit) {
    const unsigned long long cand = thr | (1ull << bit);
    const int cnt = __popcll(__ballot(k0 >= cand)) + __popcll(__ballot(k1 >= cand));
    if (cnt >= TK) thr = cand;
  }
  if (thr != 0) {  // thr==0 only if <16 keys total (impossible; pad stays)
    const unsigned long long ml = (lane == 0) ? 0ull : (~0ull >> (64 - lane));
    const unsigned long long b0 = __ballot(k0 >= thr);
    const unsigned long long b1 = __ballot(k1 >= thr);
    const int n0 = __popcll(b0);
    if (k0 >= thr) {
      const int r = __popcll(b0 & ml);
      if (r < TK) selc[wave][r] = (ushort_t)c0;
    }
    if (k1 >= thr) {
      const int r = n0 + __popcll(b1 & ml);
      if (r < TK) selc[wave][r] = (ushort_t)c1;
    }
  }
  __syncthreads();

  float acc = 0.f;
#pragma unroll
  for (int t = 0; t < TK; ++t)
    acc += nfb[(size_t)selc[wave][t] * RC + lane];  // coalesced 256B per t
  corr[(size_t)row * RC + lane] = acc * 0.0625f;
}

// ---------------- K4: proj back to C channels + residual add ----------------
// grid: 72 pixgroups x 8 channel-eighths = 576
__global__ __launch_bounds__(256) void k_proj_add(
    const float* __restrict__ x, const float* __restrict__ wp,
    const float* __restrict__ corr, float* __restrict__ out) {
  const int pg = blockIdx.x >> 3, cq = blockIdx.x & 7;
  const int tid = threadIdx.x;

  __shared__ float wl[32 * RC];  // 8 KB
  {
    const float4* src = (const float4*)(wp + (size_t)cq * 32 * RC);
    float4* dst = (float4*)wl;
#pragma unroll
    for (int i = 0; i < 2; ++i) dst[i * 256 + tid] = src[i * 256 + tid];
  }

  const int p = pg * 256 + tid;
  const int b = p >= NPIX;
  const int n = p - b * NPIX;

  float4 cr[16];
  const float4* c4 = (const float4*)(corr + (size_t)p * RC);
#pragma unroll
  for (int i = 0; i < 16; ++i) cr[i] = c4[i];
  __syncthreads();

  const size_t xb = (size_t)b * NC * NPIX + n;
  for (int cl = 0; cl < 32; ++cl) {
    const float4* w4 = (const float4*)(wl + cl * RC);  // broadcast
    float s = 0.f;
#pragma unroll
    for (int i = 0; i < 16; ++i) {
      float4 w = w4[i];
      s += w.x * cr[i].x + w.y * cr[i].y + w.z * cr[i].z + w.w * cr[i].w;
    }
    const int c = cq * 32 + cl;
    const size_t oi = xb + (size_t)c * NPIX;
    out[oi] = x[oi] + s;  // coalesced
  }
}

extern "C" void kernel_launch(void* const* d_in, const int* in_sizes, int n_in,
                              void* d_out, int out_size, void* d_ws, size_t ws_size,
                              hipStream_t stream) {
  const float* x = (const float*)d_in[0];
  const float* wr = (const float*)d_in[1];
  const float* wp = (const float*)d_in[2];
  float* out = (float*)d_out;

  char* ws = (char*)d_ws;
  // region1 (18,874,368 B) time-shares: feat4 (reduce->normsplit),
  // tmax (sim_max->thresh), corr (merge->proj) — lifetimes disjoint.
  float* feat4 = (float*)ws;
  float* tmax = (float*)ws;
  float* corr = (float*)ws;
  float* nf = (float*)(ws + 18874368);
  ushort_t* nf_hi = (ushort_t*)(ws + 23592960);
  float* Tb = (float*)(ws + 25952256);
  int* rowcnt = (int*)(ws + 26025984);
  int* cidx = (int*)(ws + 26099712);
  // total 35,536,896 B

  hipLaunchKernelGGL(k_reduce, dim3(1152), dim3(256), 0, stream, x, wr, feat4);
  hipLaunchKernelGGL(k_normsplit, dim3(288), dim3(256), 0, stream, feat4, nf, nf_hi);
  hipLaunchKernelGGL(k_sim_max, dim3(1152), dim3(256), 0, stream, nf_hi, tmax);
  hipLaunchKernelGGL(k_thresh, dim3(NROWS / 4), dim3(256), 0, stream, tmax, Tb);
  hipMemsetAsync(rowcnt, 0, NROWS * sizeof(int), stream);
  hipLaunchKernelGGL(k_collect, dim3(1152), dim3(256), 0, stream,
                     nf_hi, Tb, cidx, rowcnt);
  hipLaunchKernelGGL(k_merge_gather, dim3(NROWS / 4), dim3(256), 0, stream,
                     nf, cidx, rowcnt, corr);
  hipLaunchKernelGGL(k_proj_add, dim3(576), dim3(256), 0, stream, x, wp, corr, out);
}

// Round 7
// 271.615 us; speedup vs baseline: 1.3485x; 1.0080x over previous
//
#include <hip/hip_runtime.h>
#include <cstdint>
#include <cstddef>

#define NPIX 9216          // 96*96
#define NB 2
#define NC 256
#define RC 64
#define TK 16
#define NROWS (NB * NPIX)  // 18432
#define CT 128             // cols per LDS tile
#define ECOLS 1152         // cols per eighth
#define NTE 9              // tiles per eighth
#define MAXC 128           // compact candidate slots per row
#define LCAP 64            // per-block per-row LDS candidate capacity
#define MARGIN 0.008f      // 2*e, e <= 2.01*2^-9 * ||a||*||b|| = 3.93e-3

typedef unsigned short ushort_t;
typedef unsigned int uint_t;
typedef __bf16 bf16x8 __attribute__((ext_vector_type(8)));
typedef float f32x4 __attribute__((ext_vector_type(4)));

__device__ __forceinline__ uint_t f2bf(float x) {
  uint_t u = __float_as_uint(x);
  return (u + 0x7FFFu + ((u >> 16) & 1u)) >> 16;
}

// monotone float->uint map (bigger float => bigger uint)
__device__ __forceinline__ uint_t ordu(float v) {
  uint_t u = __float_as_uint(v);
  return (u & 0x80000000u) ? ~u : (u | 0x80000000u);
}

// async global->LDS, 16B per lane. dest is wave-uniform base (HW adds lane*16).
#define GL2LDS(gsrc, ldst)                                                   \
  __builtin_amdgcn_global_load_lds(                                          \
      (const __attribute__((address_space(1))) uint_t*)(const void*)(gsrc),  \
      (__attribute__((address_space(3))) uint_t*)(void*)(ldst), 16, 0, 0)

// Stage one 128x64 bf16 tile (16 KB) via global_load_lds.
// LDS is linear [128][64]; source is pre-swizzled so that physical 16B-slot s
// of row r holds global slot s^(r&7) (rule #21: linear dest + swizzled source).
__device__ __forceinline__ void stage_tile(
    const ushort_t* __restrict__ nf_hi, size_t cbase, int cb,
    ushort_t* shbuf, int tid) {
  const int wave = tid >> 6, l = tid & 63;
  const int lr = l >> 3;             // row within 8-row group
  const int ls = (l & 7) ^ lr;       // swizzled global slot
#pragma unroll
  for (int i = 0; i < 4; ++i) {
    const int j = wave * 4 + i;      // instruction covers rows 8j..8j+7
    const ushort_t* g = nf_hi + (cbase + (size_t)(cb + j * 8 + lr)) * 64 + ls * 8;
    ushort_t* d = shbuf + j * 512;   // 1024 B per instruction, wave-uniform
    GL2LDS(g, d);
  }
}

// ---------------- K1: 1x1 conv reduce, c-split partials ----------------
// grid: 72 pixgroups x 4 rq x 4 cq = 1152. feat4 layout [rq*4+cq][NROWS][16]
__global__ __launch_bounds__(256) void k_reduce(
    const float* __restrict__ x, const float* __restrict__ wr,
    float* __restrict__ feat4) {
  __shared__ float wl[64 * 16];  // 4 KB: [c_local][r_local]
  const int bi = blockIdx.x;
  const int pg = bi >> 4, rq = (bi >> 2) & 3, cq = bi & 3;
  const int tid = threadIdx.x;
  {
    const int cl = tid >> 2, rg = (tid & 3) * 4;
#pragma unroll
    for (int i = 0; i < 4; ++i)
      wl[cl * 16 + rg + i] = wr[(size_t)(rq * 16 + rg + i) * NC + cq * 64 + cl];
  }
  __syncthreads();

  const int p = pg * 256 + tid;
  const int b = p >= NPIX;
  const int n = p - b * NPIX;
  const float* xp = x + (size_t)b * NC * NPIX + (size_t)cq * 64 * NPIX + n;

  float4 acc[4];
#pragma unroll
  for (int i = 0; i < 4; ++i) acc[i] = make_float4(0.f, 0.f, 0.f, 0.f);

  for (int c = 0; c < 64; ++c) {
    const float xv = xp[(size_t)c * NPIX];           // coalesced
    const float4* w4 = (const float4*)(wl + c * 16); // broadcast
#pragma unroll
    for (int i = 0; i < 4; ++i) {
      float4 w = w4[i];
      acc[i].x += w.x * xv; acc[i].y += w.y * xv;
      acc[i].z += w.z * xv; acc[i].w += w.w * xv;
    }
  }
  float4* o = (float4*)(feat4 + (((size_t)(rq * 4 + cq)) * NROWS + p) * 16);
#pragma unroll
  for (int i = 0; i < 4; ++i) o[i] = acc[i];  // 64B/lane contiguous
}

// ---------------- K1b: sum partials + normalize + bf16 hi ----------------
__global__ __launch_bounds__(256) void k_normsplit(
    const float* __restrict__ feat4, float* __restrict__ nf,
    ushort_t* __restrict__ hi) {
  const int t = blockIdx.x * 256 + threadIdx.x;
  const int p = t >> 2, q = t & 3;  // 4 lanes per pixel
  float4 v[4];
#pragma unroll
  for (int i = 0; i < 4; ++i) v[i] = make_float4(0.f, 0.f, 0.f, 0.f);
#pragma unroll
  for (int pt = 0; pt < 4; ++pt) {
    const float4* fp = (const float4*)(feat4 + (((size_t)(q * 4 + pt)) * NROWS + p) * 16);
#pragma unroll
    for (int i = 0; i < 4; ++i) {
      float4 a = fp[i];
      v[i].x += a.x; v[i].y += a.y; v[i].z += a.z; v[i].w += a.w;
    }
  }
  float ssq = 0.f;
#pragma unroll
  for (int i = 0; i < 4; ++i)
    ssq += v[i].x * v[i].x + v[i].y * v[i].y + v[i].z * v[i].z + v[i].w * v[i].w;
  ssq += __shfl_xor(ssq, 1);
  ssq += __shfl_xor(ssq, 2);
  const float inv = 1.f / fmaxf(sqrtf(ssq), 1e-12f);

  float s[16];
#pragma unroll
  for (int i = 0; i < 4; ++i) {
    s[i * 4 + 0] = v[i].x * inv; s[i * 4 + 1] = v[i].y * inv;
    s[i * 4 + 2] = v[i].z * inv; s[i * 4 + 3] = v[i].w * inv;
  }
  float4* no = (float4*)(nf + (size_t)p * RC + q * 16);
#pragma unroll
  for (int i = 0; i < 4; ++i)
    no[i] = make_float4(s[i * 4], s[i * 4 + 1], s[i * 4 + 2], s[i * 4 + 3]);

  uint_t hs[16];
#pragma unroll
  for (int i = 0; i < 16; ++i) hs[i] = f2bf(s[i]);
  uint4* ho = (uint4*)(hi + (size_t)p * RC + q * 16);
#pragma unroll
  for (int h = 0; h < 2; ++h)
    ho[h] = make_uint4(hs[h*8+0] | (hs[h*8+1] << 16), hs[h*8+2] | (hs[h*8+3] << 16),
                       hs[h*8+4] | (hs[h*8+5] << 16), hs[h*8+6] | (hs[h*8+7] << 16));
}

// ---------------- K2a: pass A — hi sims, per-lane chunk maxima ----------------
// grid: 144 rowblocks(128 rows) x 8 col-eighths = 1152.
// T3-minimum 2-phase pipeline (statically-named shA/shB, no runtime buffer
// index): issue STAGE(next) BEFORE compute(cur); ONE __syncthreads (vmcnt
// drain) per tile. Stage latency hides under the MFMA phase.
__global__ __launch_bounds__(256) void k_sim_max(
    const ushort_t* __restrict__ nf_hi, float* __restrict__ tmax) {
  __shared__ ushort_t shA[CT * 64];  // 16 KB
  __shared__ ushort_t shB[CT * 64];  // 16 KB
  const int rb = blockIdx.x >> 3, q = blockIdx.x & 7;
  const int tid = threadIdx.x, wave = tid >> 6, lane = tid & 63;
  const int n = lane & 15, quad = lane >> 4;
  const int r0 = rb * 128 + wave * 32 + n, r1 = r0 + 16;
  const int b = rb >= 72;
  const size_t cbase = (size_t)b * NPIX;
  const int x0 = (quad ^ (n & 7)) * 8;        // swizzled slot offsets (ushorts)
  const int x1 = ((quad + 4) ^ (n & 7)) * 8;

  const bf16x8 bh00 = *(const bf16x8*)(nf_hi + (size_t)r0 * 64 + quad * 8);
  const bf16x8 bh01 = *(const bf16x8*)(nf_hi + (size_t)r0 * 64 + 32 + quad * 8);
  const bf16x8 bh10 = *(const bf16x8*)(nf_hi + (size_t)r1 * 64 + quad * 8);
  const bf16x8 bh11 = *(const bf16x8*)(nf_hi + (size_t)r1 * 64 + 32 + quad * 8);

  float cm0 = -1e30f, cm1 = -1e30f;

  auto compute = [&](const ushort_t* shc, int t) {
#pragma unroll
    for (int st = 0; st < 8; ++st) {
      const ushort_t* ap = shc + (st * 16 + n) * 64;
      bf16x8 ah0 = *(const bf16x8*)(ap + x0);
      bf16x8 ah1 = *(const bf16x8*)(ap + x1);
      f32x4 z = {0.f, 0.f, 0.f, 0.f};
      f32x4 a0 = __builtin_amdgcn_mfma_f32_16x16x32_bf16(ah0, bh00, z, 0, 0, 0);
      a0 = __builtin_amdgcn_mfma_f32_16x16x32_bf16(ah1, bh01, a0, 0, 0, 0);
      f32x4 a1 = __builtin_amdgcn_mfma_f32_16x16x32_bf16(ah0, bh10, z, 0, 0, 0);
      a1 = __builtin_amdgcn_mfma_f32_16x16x32_bf16(ah1, bh11, a1, 0, 0, 0);
      cm0 = fmaxf(fmaxf(a0[0], a0[1]), fmaxf(fmaxf(a0[2], a0[3]), cm0));
      cm1 = fmaxf(fmaxf(a1[0], a1[1]), fmaxf(fmaxf(a1[2], a1[3]), cm1));
    }
    if (t % 3 == 2) {  // 3 tiles = 96 cols per lane-stream chunk
      const int cn = t / 3;
      tmax[(size_t)r0 * 96 + (q * 4 + quad) * 3 + cn] = cm0;
      tmax[(size_t)r1 * 96 + (q * 4 + quad) * 3 + cn] = cm1;
      cm0 = -1e30f; cm1 = -1e30f;
    }
  };

  stage_tile(nf_hi, cbase, q * ECOLS, shA, tid);
  __syncthreads();  // tile 0 resident
#pragma unroll 1
  for (int t = 0; t < NTE - 1; t += 2) {         // t = 0,2,4,6
    stage_tile(nf_hi, cbase, q * ECOLS + (t + 1) * CT, shB, tid);
    compute(shA, t);
    __syncthreads();  // drains shB prefetch; shA readers done
    stage_tile(nf_hi, cbase, q * ECOLS + (t + 2) * CT, shA, tid);
    compute(shB, t + 1);
    __syncthreads();  // drains shA prefetch; shB readers done
  }
  compute(shA, NTE - 1);  // tile 8
}

// ---------------- K2b: threshold = 16th largest of 96 chunk maxima - margin ----------------
__global__ __launch_bounds__(256) void k_thresh(
    const float* __restrict__ tmax, float* __restrict__ Tb) {
  const int wave = threadIdx.x >> 6, lane = threadIdx.x & 63;
  const int row = blockIdx.x * 4 + wave;
  const float* tp = tmax + (size_t)row * 96;
  float v0 = tp[lane];
  float v1 = (lane < 32) ? tp[64 + lane] : -1e30f;
  float m = -1e30f;
#pragma unroll
  for (int k = 0; k < TK; ++k) {
    float c = fmaxf(v0, v1);
#pragma unroll
    for (int d = 1; d < 64; d <<= 1) c = fmaxf(c, __shfl_xor(c, d));
    m = c;
    if (v0 == m) v0 = -1e30f;  // killing duplicates only lowers T: safe
    if (v1 == m) v1 = -1e30f;
  }
  if (lane == 0) Tb[row] = m - MARGIN;
}

// ---------------- K2c: pass B — hi sims again, collect cols with s_hi >= T ----------------
// Same 2-phase pipeline; candidates go to per-row LDS lists (block-local
// atomics); ONE global atomicAdd per row per block at flush.
__global__ __launch_bounds__(256) void k_collect(
    const ushort_t* __restrict__ nf_hi, const float* __restrict__ Tb,
    int* __restrict__ cidx, int* __restrict__ rowcnt) {
  __shared__ ushort_t shA[CT * 64];         // 16 KB
  __shared__ ushort_t shB[CT * 64];         // 16 KB
  __shared__ ushort_t lst[128][LCAP + 1];   // 16.6 KB per-row candidate lists
  __shared__ int lcnt[128];                 // 512 B
  const int rb = blockIdx.x >> 3, q = blockIdx.x & 7;
  const int tid = threadIdx.x, wave = tid >> 6, lane = tid & 63;
  const int n = lane & 15, quad = lane >> 4;
  const int rl0 = wave * 32 + n, rl1 = rl0 + 16;  // row-local ids in [0,128)
  const int r0 = rb * 128 + rl0, r1 = r0 + 16;
  const int b = rb >= 72;
  const size_t cbase = (size_t)b * NPIX;
  const int x0 = (quad ^ (n & 7)) * 8;
  const int x1 = ((quad + 4) ^ (n & 7)) * 8;

  if (tid < 128) lcnt[tid] = 0;

  const bf16x8 bh00 = *(const bf16x8*)(nf_hi + (size_t)r0 * 64 + quad * 8);
  const bf16x8 bh01 = *(const bf16x8*)(nf_hi + (size_t)r0 * 64 + 32 + quad * 8);
  const bf16x8 bh10 = *(const bf16x8*)(nf_hi + (size_t)r1 * 64 + quad * 8);
  const bf16x8 bh11 = *(const bf16x8*)(nf_hi + (size_t)r1 * 64 + 32 + quad * 8);

  const float T0 = Tb[r0], T1 = Tb[r1];

  auto compute = [&](const ushort_t* shc, int t) {
    const int cb = q * ECOLS + t * CT;
#pragma unroll
    for (int st = 0; st < 8; ++st) {
      const ushort_t* ap = shc + (st * 16 + n) * 64;
      bf16x8 ah0 = *(const bf16x8*)(ap + x0);
      bf16x8 ah1 = *(const bf16x8*)(ap + x1);
      f32x4 z = {0.f, 0.f, 0.f, 0.f};
      f32x4 a0 = __builtin_amdgcn_mfma_f32_16x16x32_bf16(ah0, bh00, z, 0, 0, 0);
      a0 = __builtin_amdgcn_mfma_f32_16x16x32_bf16(ah1, bh01, a0, 0, 0, 0);
      f32x4 a1 = __builtin_amdgcn_mfma_f32_16x16x32_bf16(ah0, bh10, z, 0, 0, 0);
      a1 = __builtin_amdgcn_mfma_f32_16x16x32_bf16(ah1, bh11, a1, 0, 0, 0);

      const int c0 = cb + st * 16 + quad * 4;
      const int m0 = (a0[0] >= T0) | ((a0[1] >= T0) << 1) |
                     ((a0[2] >= T0) << 2) | ((a0[3] >= T0) << 3);
      if (m0) {
        int slot = atomicAdd(&lcnt[rl0], __popc(m0));  // LDS atomic, block-local
#pragma unroll
        for (int r = 0; r < 4; ++r)
          if (m0 & (1 << r)) {
            if (slot < LCAP) lst[rl0][slot] = (ushort_t)(c0 + r);
            ++slot;
          }
      }
      const int m1 = (a1[0] >= T1) | ((a1[1] >= T1) << 1) |
                     ((a1[2] >= T1) << 2) | ((a1[3] >= T1) << 3);
      if (m1) {
        int slot = atomicAdd(&lcnt[rl1], __popc(m1));
#pragma unroll
        for (int r = 0; r < 4; ++r)
          if (m1 & (1 << r)) {
            if (slot < LCAP) lst[rl1][slot] = (ushort_t)(c0 + r);
            ++slot;
          }
      }
    }
  };

  stage_tile(nf_hi, cbase, q * ECOLS, shA, tid);
  __syncthreads();  // tile 0 resident (also covers lcnt init)
#pragma unroll 1
  for (int t = 0; t < NTE - 1; t += 2) {         // t = 0,2,4,6
    stage_tile(nf_hi, cbase, q * ECOLS + (t + 1) * CT, shB, tid);
    compute(shA, t);
    __syncthreads();
    stage_tile(nf_hi, cbase, q * ECOLS + (t + 2) * CT, shA, tid);
    compute(shB, t + 1);
    __syncthreads();
  }
  compute(shA, NTE - 1);  // tile 8
  __syncthreads();
  // flush: one global reservation per row, 128 rows by threads 0..127 (parallel atomics)
  if (tid < 128) {
    const int row = rb * 128 + tid;
    const int cnt = min(lcnt[tid], LCAP);
    int base = atomicAdd(rowcnt + row, cnt);
    for (int j = 0; j < cnt; ++j) {
      const int gs = base + j;
      if (gs < MAXC) cidx[(size_t)row * MAXC + gs] = (int)lst[tid][j];
    }
  }
}

// ---------------- K3: exact fp32 dots on candidates + top-16 + gather + mean ----------------
// wave per row; grid NROWS/4 = 4608 blocks x 4 waves.
// top-16 via 64-bit ballot-bisection (keys distinct => exactly 16 selected).
__global__ __launch_bounds__(256) void k_merge_gather(
    const float* __restrict__ nf, const int* __restrict__ cidx,
    const int* __restrict__ rowcnt, float* __restrict__ corr) {
  __shared__ ushort_t selc[4][TK];
  const int wave = threadIdx.x >> 6, lane = threadIdx.x & 63;
  const int row = blockIdx.x * 4 + wave;
  const int b = row >= NPIX;
  const int rl = row - b * NPIX;
  const float* nfb = nf + (size_t)b * NPIX * RC;
  const int C = min(rowcnt[row], MAXC);

  if (lane < TK) selc[wave][lane] = (ushort_t)rl;  // safety pad (C<16 impossible by construction)
  __syncthreads();

  float4 rv[16];
  const float4* r4 = (const float4*)(nf + (size_t)row * RC);
#pragma unroll
  for (int i = 0; i < 16; ++i) rv[i] = r4[i];  // broadcast loads

  const int* cp = cidx + (size_t)row * MAXC;
  unsigned long long k0 = 0, k1 = 0;
  int c0 = rl, c1 = rl;
  {
    c0 = (lane < C) ? cp[lane] : rl;
    const float4* g = (const float4*)(nfb + (size_t)c0 * RC);
    float s = 0.f;
#pragma unroll
    for (int i = 0; i < 16; ++i) {
      float4 a = g[i];
      s += a.x * rv[i].x + a.y * rv[i].y + a.z * rv[i].z + a.w * rv[i].w;
    }
    if (lane < C)
      k0 = ((unsigned long long)ordu(s) << 32) | (uint_t)(~(uint_t)c0);
  }
  if (C > 64) {  // wave-uniform branch, rare
    c1 = (64 + lane < C) ? cp[64 + lane] : rl;
    const float4* g = (const float4*)(nfb + (size_t)c1 * RC);
    float s = 0.f;
#pragma unroll
    for (int i = 0; i < 16; ++i) {
      float4 a = g[i];
      s += a.x * rv[i].x + a.y * rv[i].y + a.z * rv[i].z + a.w * rv[i].w;
    }
    if (64 + lane < C)
      k1 = ((unsigned long long)ordu(s) << 32) | (uint_t)(~(uint_t)c1);
  }

  // bisection: largest thr with |{keys >= thr}| >= 16; distinct keys => exactly 16
  unsigned long long thr = 0;
#pragma unroll
  for (int bit = 63; bit >= 0; --bit) {
    const unsigned long long cand = thr | (1ull << bit);
    const int cnt = __popcll(__ballot(k0 >= cand)) + __popcll(__ballot(k1 >= cand));
    if (cnt >= TK) thr = cand;
  }
  if (thr != 0) {  // thr==0 only if <16 keys total (impossible; pad stays)
    const unsigned long long ml = (lane == 0) ? 0ull : (~0ull >> (64 - lane));
    const unsigned long long b0 = __ballot(k0 >= thr);
    const unsigned long long b1 = __ballot(k1 >= thr);
    const int n0 = __popcll(b0);
    if (k0 >= thr) {
      const int r = __popcll(b0 & ml);
      if (r < TK) selc[wave][r] = (ushort_t)c0;
    }
    if (k1 >= thr) {
      const int r = n0 + __popcll(b1 & ml);
      if (r < TK) selc[wave][r] = (ushort_t)c1;
    }
  }
  __syncthreads();

  float acc = 0.f;
#pragma unroll
  for (int t = 0; t < TK; ++t)
    acc += nfb[(size_t)selc[wave][t] * RC + lane];  // coalesced 256B per t
  corr[(size_t)row * RC + lane] = acc * 0.0625f;
}

// ---------------- K4: proj back to C channels + residual add ----------------
// grid: 72 pixgroups x 8 channel-eighths = 576
__global__ __launch_bounds__(256) void k_proj_add(
    const float* __restrict__ x, const float* __restrict__ wp,
    const float* __restrict__ corr, float* __restrict__ out) {
  const int pg = blockIdx.x >> 3, cq = blockIdx.x & 7;
  const int tid = threadIdx.x;

  __shared__ float wl[32 * RC];  // 8 KB
  {
    const float4* src = (const float4*)(wp + (size_t)cq * 32 * RC);
    float4* dst = (float4*)wl;
#pragma unroll
    for (int i = 0; i < 2; ++i) dst[i * 256 + tid] = src[i * 256 + tid];
  }

  const int p = pg * 256 + tid;
  const int b = p >= NPIX;
  const int n = p - b * NPIX;

  float4 cr[16];
  const float4* c4 = (const float4*)(corr + (size_t)p * RC);
#pragma unroll
  for (int i = 0; i < 16; ++i) cr[i] = c4[i];
  __syncthreads();

  const size_t xb = (size_t)b * NC * NPIX + n;
  for (int cl = 0; cl < 32; ++cl) {
    const float4* w4 = (const float4*)(wl + cl * RC);  // broadcast
    float s = 0.f;
#pragma unroll
    for (int i = 0; i < 16; ++i) {
      float4 w = w4[i];
      s += w.x * cr[i].x + w.y * cr[i].y + w.z * cr[i].z + w.w * cr[i].w;
    }
    const int c = cq * 32 + cl;
    const size_t oi = xb + (size_t)c * NPIX;
    out[oi] = x[oi] + s;  // coalesced
  }
}

extern "C" void kernel_launch(void* const* d_in, const int* in_sizes, int n_in,
                              void* d_out, int out_size, void* d_ws, size_t ws_size,
                              hipStream_t stream) {
  const float* x = (const float*)d_in[0];
  const float* wr = (const float*)d_in[1];
  const float* wp = (const float*)d_in[2];
  float* out = (float*)d_out;

  char* ws = (char*)d_ws;
  // region1 (18,874,368 B) time-shares: feat4 (reduce->normsplit),
  // tmax (sim_max->thresh), corr (merge->proj) — lifetimes disjoint.
  float* feat4 = (float*)ws;
  float* tmax = (float*)ws;
  float* corr = (float*)ws;
  float* nf = (float*)(ws + 18874368);
  ushort_t* nf_hi = (ushort_t*)(ws + 23592960);
  float* Tb = (float*)(ws + 25952256);
  int* rowcnt = (int*)(ws + 26025984);
  int* cidx = (int*)(ws + 26099712);
  // total 35,536,896 B

  hipLaunchKernelGGL(k_reduce, dim3(1152), dim3(256), 0, stream, x, wr, feat4);
  hipLaunchKernelGGL(k_normsplit, dim3(288), dim3(256), 0, stream, feat4, nf, nf_hi);
  hipLaunchKernelGGL(k_sim_max, dim3(1152), dim3(256), 0, stream, nf_hi, tmax);
  hipLaunchKernelGGL(k_thresh, dim3(NROWS / 4), dim3(256), 0, stream, tmax, Tb);
  hipMemsetAsync(rowcnt, 0, NROWS * sizeof(int), stream);
  hipLaunchKernelGGL(k_collect, dim3(1152), dim3(256), 0, stream,
                     nf_hi, Tb, cidx, rowcnt);
  hipLaunchKernelGGL(k_merge_gather, dim3(NROWS / 4), dim3(256), 0, stream,
                     nf, cidx, rowcnt, corr);
  hipLaunchKernelGGL(k_proj_add, dim3(576), dim3(256), 0, stream, x, wp, corr, out);
}

// Round 8
// 256.411 us; speedup vs baseline: 1.4284x; 1.0593x over previous
//
#include <hip/hip_runtime.h>
#include <cstdint>
#include <cstddef>

#define NPIX 9216          // 96*96
#define NB 2
#define NC 256
#define RC 64
#define TK 16
#define NROWS (NB * NPIX)  // 18432
#define CT 128             // cols per LDS tile
#define NQ 12              // col splits per batch
#define ECOLS 768          // cols per split (6 tiles)
#define NTE 6              // tiles per split
#define MAXC 128           // compact candidate slots per row
#define LCAP 48            // per-block per-row LDS candidate capacity
#define MARGIN 0.008f      // 2*e, e <= 2.01*2^-9 * ||a||*||b|| = 3.93e-3

typedef unsigned short ushort_t;
typedef unsigned int uint_t;
typedef __bf16 bf16x8 __attribute__((ext_vector_type(8)));
typedef float f32x4 __attribute__((ext_vector_type(4)));

__device__ __forceinline__ uint_t f2bf(float x) {
  uint_t u = __float_as_uint(x);
  return (u + 0x7FFFu + ((u >> 16) & 1u)) >> 16;
}

// monotone float->uint map (bigger float => bigger uint)
__device__ __forceinline__ uint_t ordu(float v) {
  uint_t u = __float_as_uint(v);
  return (u & 0x80000000u) ? ~u : (u | 0x80000000u);
}

// async global->LDS, 16B per lane. dest is wave-uniform base (HW adds lane*16).
#define GL2LDS(gsrc, ldst)                                                   \
  __builtin_amdgcn_global_load_lds(                                          \
      (const __attribute__((address_space(1))) uint_t*)(const void*)(gsrc),  \
      (__attribute__((address_space(3))) uint_t*)(void*)(ldst), 16, 0, 0)

// Stage one 128x64 bf16 tile (16 KB) via global_load_lds.
// LDS is linear [128][64]; source is pre-swizzled so that physical 16B-slot s
// of row r holds global slot s^(r&7) (rule #21: linear dest + swizzled source).
__device__ __forceinline__ void stage_tile(
    const ushort_t* __restrict__ nf_hi, size_t cbase, int cb,
    ushort_t* shbuf, int tid) {
  const int wave = tid >> 6, l = tid & 63;
  const int lr = l >> 3;             // row within 8-row group
  const int ls = (l & 7) ^ lr;       // swizzled global slot
#pragma unroll
  for (int i = 0; i < 4; ++i) {
    const int j = wave * 4 + i;      // instruction covers rows 8j..8j+7
    const ushort_t* g = nf_hi + (cbase + (size_t)(cb + j * 8 + lr)) * 64 + ls * 8;
    ushort_t* d = shbuf + j * 512;   // 1024 B per instruction, wave-uniform
    GL2LDS(g, d);
  }
}

// ---------------- K1: 1x1 conv reduce, c-split partials ----------------
// grid: 72 pixgroups x 4 rq x 4 cq = 1152. feat4 layout [rq*4+cq][NROWS][16]
__global__ __launch_bounds__(256) void k_reduce(
    const float* __restrict__ x, const float* __restrict__ wr,
    float* __restrict__ feat4) {
  __shared__ float wl[64 * 16];  // 4 KB: [c_local][r_local]
  const int bi = blockIdx.x;
  const int pg = bi >> 4, rq = (bi >> 2) & 3, cq = bi & 3;
  const int tid = threadIdx.x;
  {
    const int cl = tid >> 2, rg = (tid & 3) * 4;
#pragma unroll
    for (int i = 0; i < 4; ++i)
      wl[cl * 16 + rg + i] = wr[(size_t)(rq * 16 + rg + i) * NC + cq * 64 + cl];
  }
  __syncthreads();

  const int p = pg * 256 + tid;
  const int b = p >= NPIX;
  const int n = p - b * NPIX;
  const float* xp = x + (size_t)b * NC * NPIX + (size_t)cq * 64 * NPIX + n;

  float4 acc[4];
#pragma unroll
  for (int i = 0; i < 4; ++i) acc[i] = make_float4(0.f, 0.f, 0.f, 0.f);

  for (int c = 0; c < 64; ++c) {
    const float xv = xp[(size_t)c * NPIX];           // coalesced
    const float4* w4 = (const float4*)(wl + c * 16); // broadcast
#pragma unroll
    for (int i = 0; i < 4; ++i) {
      float4 w = w4[i];
      acc[i].x += w.x * xv; acc[i].y += w.y * xv;
      acc[i].z += w.z * xv; acc[i].w += w.w * xv;
    }
  }
  float4* o = (float4*)(feat4 + (((size_t)(rq * 4 + cq)) * NROWS + p) * 16);
#pragma unroll
  for (int i = 0; i < 4; ++i) o[i] = acc[i];  // 64B/lane contiguous
}

// ---------------- K1b: sum partials + normalize + bf16 hi ----------------
__global__ __launch_bounds__(256) void k_normsplit(
    const float* __restrict__ feat4, float* __restrict__ nf,
    ushort_t* __restrict__ hi) {
  const int t = blockIdx.x * 256 + threadIdx.x;
  const int p = t >> 2, q = t & 3;  // 4 lanes per pixel
  float4 v[4];
#pragma unroll
  for (int i = 0; i < 4; ++i) v[i] = make_float4(0.f, 0.f, 0.f, 0.f);
#pragma unroll
  for (int pt = 0; pt < 4; ++pt) {
    const float4* fp = (const float4*)(feat4 + (((size_t)(q * 4 + pt)) * NROWS + p) * 16);
#pragma unroll
    for (int i = 0; i < 4; ++i) {
      float4 a = fp[i];
      v[i].x += a.x; v[i].y += a.y; v[i].z += a.z; v[i].w += a.w;
    }
  }
  float ssq = 0.f;
#pragma unroll
  for (int i = 0; i < 4; ++i)
    ssq += v[i].x * v[i].x + v[i].y * v[i].y + v[i].z * v[i].z + v[i].w * v[i].w;
  ssq += __shfl_xor(ssq, 1);
  ssq += __shfl_xor(ssq, 2);
  const float inv = 1.f / fmaxf(sqrtf(ssq), 1e-12f);

  float s[16];
#pragma unroll
  for (int i = 0; i < 4; ++i) {
    s[i * 4 + 0] = v[i].x * inv; s[i * 4 + 1] = v[i].y * inv;
    s[i * 4 + 2] = v[i].z * inv; s[i * 4 + 3] = v[i].w * inv;
  }
  float4* no = (float4*)(nf + (size_t)p * RC + q * 16);
#pragma unroll
  for (int i = 0; i < 4; ++i)
    no[i] = make_float4(s[i * 4], s[i * 4 + 1], s[i * 4 + 2], s[i * 4 + 3]);

  uint_t hs[16];
#pragma unroll
  for (int i = 0; i < 16; ++i) hs[i] = f2bf(s[i]);
  uint4* ho = (uint4*)(hi + (size_t)p * RC + q * 16);
#pragma unroll
  for (int h = 0; h < 2; ++h)
    ho[h] = make_uint4(hs[h*8+0] | (hs[h*8+1] << 16), hs[h*8+2] | (hs[h*8+3] << 16),
                       hs[h*8+4] | (hs[h*8+5] << 16), hs[h*8+6] | (hs[h*8+7] << 16));
}

// ---------------- K2a: pass A — hi sims, per-lane chunk maxima ----------------
// grid: 144 rowblocks(128 rows) x 12 col-splits = 1728.
// Single 16 KB buffer (r5 schedule; 2-phase measured null) — occupancy is
// the lever: ~7 blocks/CU grid supply, LDS cap 10.
__global__ __launch_bounds__(256) void k_sim_max(
    const ushort_t* __restrict__ nf_hi, float* __restrict__ tmax) {
  __shared__ ushort_t sh[CT * 64];  // 16 KB linear
  const int rb = blockIdx.x / NQ, q = blockIdx.x % NQ;
  const int tid = threadIdx.x, wave = tid >> 6, lane = tid & 63;
  const int n = lane & 15, quad = lane >> 4;
  const int r0 = rb * 128 + wave * 32 + n, r1 = r0 + 16;
  const int b = rb >= 72;
  const size_t cbase = (size_t)b * NPIX;
  const int x0 = (quad ^ (n & 7)) * 8;        // swizzled slot offsets (ushorts)
  const int x1 = ((quad + 4) ^ (n & 7)) * 8;

  const bf16x8 bh00 = *(const bf16x8*)(nf_hi + (size_t)r0 * 64 + quad * 8);
  const bf16x8 bh01 = *(const bf16x8*)(nf_hi + (size_t)r0 * 64 + 32 + quad * 8);
  const bf16x8 bh10 = *(const bf16x8*)(nf_hi + (size_t)r1 * 64 + quad * 8);
  const bf16x8 bh11 = *(const bf16x8*)(nf_hi + (size_t)r1 * 64 + 32 + quad * 8);

  float cm0 = -1e30f, cm1 = -1e30f;

  for (int t = 0; t < NTE; ++t) {
    stage_tile(nf_hi, cbase, q * ECOLS + t * CT, sh, tid);
    __syncthreads();  // drains vmcnt(0): tile resident

#pragma unroll
    for (int st = 0; st < 8; ++st) {
      const ushort_t* ap = sh + (st * 16 + n) * 64;
      bf16x8 ah0 = *(const bf16x8*)(ap + x0);
      bf16x8 ah1 = *(const bf16x8*)(ap + x1);
      f32x4 z = {0.f, 0.f, 0.f, 0.f};
      f32x4 a0 = __builtin_amdgcn_mfma_f32_16x16x32_bf16(ah0, bh00, z, 0, 0, 0);
      a0 = __builtin_amdgcn_mfma_f32_16x16x32_bf16(ah1, bh01, a0, 0, 0, 0);
      f32x4 a1 = __builtin_amdgcn_mfma_f32_16x16x32_bf16(ah0, bh10, z, 0, 0, 0);
      a1 = __builtin_amdgcn_mfma_f32_16x16x32_bf16(ah1, bh11, a1, 0, 0, 0);
      cm0 = fmaxf(fmaxf(a0[0], a0[1]), fmaxf(fmaxf(a0[2], a0[3]), cm0));
      cm1 = fmaxf(fmaxf(a1[0], a1[1]), fmaxf(fmaxf(a1[2], a1[3]), cm1));
    }
    if (t % 3 == 2) {  // 3 tiles = 96 cols per lane-stream chunk
      const int cn = t / 3;
      tmax[(size_t)r0 * 96 + (q * 4 + quad) * 2 + cn] = cm0;
      tmax[(size_t)r1 * 96 + (q * 4 + quad) * 2 + cn] = cm1;
      cm0 = -1e30f; cm1 = -1e30f;
    }
    __syncthreads();  // readers done before next stage overwrites
  }
}

// ---------------- K2b: threshold = 16th largest of 96 chunk maxima - margin ----------------
__global__ __launch_bounds__(256) void k_thresh(
    const float* __restrict__ tmax, float* __restrict__ Tb) {
  const int wave = threadIdx.x >> 6, lane = threadIdx.x & 63;
  const int row = blockIdx.x * 4 + wave;
  const float* tp = tmax + (size_t)row * 96;
  float v0 = tp[lane];
  float v1 = (lane < 32) ? tp[64 + lane] : -1e30f;
  float m = -1e30f;
#pragma unroll
  for (int k = 0; k < TK; ++k) {
    float c = fmaxf(v0, v1);
#pragma unroll
    for (int d = 1; d < 64; d <<= 1) c = fmaxf(c, __shfl_xor(c, d));
    m = c;
    if (v0 == m) v0 = -1e30f;  // killing duplicates only lowers T: safe
    if (v1 == m) v1 = -1e30f;
  }
  if (lane == 0) Tb[row] = m - MARGIN;
}

// ---------------- K2c: pass B — hi sims again, collect cols with s_hi >= T ----------------
// Single-buffer r5 schedule; candidates to per-row LDS lists (block-local
// atomics); ONE global atomicAdd per row per block at flush. LDS 29.4 KB
// -> 5 blocks/CU.
__global__ __launch_bounds__(256) void k_collect(
    const ushort_t* __restrict__ nf_hi, const float* __restrict__ Tb,
    int* __restrict__ cidx, int* __restrict__ rowcnt) {
  __shared__ ushort_t sh[CT * 64];          // 16 KB staging
  __shared__ ushort_t lst[128][LCAP + 1];   // 12.5 KB per-row candidate lists
  __shared__ int lcnt[128];                 // 512 B
  const int rb = blockIdx.x / NQ, q = blockIdx.x % NQ;
  const int tid = threadIdx.x, wave = tid >> 6, lane = tid & 63;
  const int n = lane & 15, quad = lane >> 4;
  const int rl0 = wave * 32 + n, rl1 = rl0 + 16;  // row-local ids in [0,128)
  const int r0 = rb * 128 + rl0, r1 = r0 + 16;
  const int b = rb >= 72;
  const size_t cbase = (size_t)b * NPIX;
  const int x0 = (quad ^ (n & 7)) * 8;
  const int x1 = ((quad + 4) ^ (n & 7)) * 8;

  if (tid < 128) lcnt[tid] = 0;

  const bf16x8 bh00 = *(const bf16x8*)(nf_hi + (size_t)r0 * 64 + quad * 8);
  const bf16x8 bh01 = *(const bf16x8*)(nf_hi + (size_t)r0 * 64 + 32 + quad * 8);
  const bf16x8 bh10 = *(const bf16x8*)(nf_hi + (size_t)r1 * 64 + quad * 8);
  const bf16x8 bh11 = *(const bf16x8*)(nf_hi + (size_t)r1 * 64 + 32 + quad * 8);

  const float T0 = Tb[r0], T1 = Tb[r1];

  for (int t = 0; t < NTE; ++t) {
    const int cb = q * ECOLS + t * CT;
    stage_tile(nf_hi, cbase, cb, sh, tid);
    __syncthreads();  // vmcnt drained: tile resident (also covers lcnt init)

#pragma unroll
    for (int st = 0; st < 8; ++st) {
      const ushort_t* ap = sh + (st * 16 + n) * 64;
      bf16x8 ah0 = *(const bf16x8*)(ap + x0);
      bf16x8 ah1 = *(const bf16x8*)(ap + x1);
      f32x4 z = {0.f, 0.f, 0.f, 0.f};
      f32x4 a0 = __builtin_amdgcn_mfma_f32_16x16x32_bf16(ah0, bh00, z, 0, 0, 0);
      a0 = __builtin_amdgcn_mfma_f32_16x16x32_bf16(ah1, bh01, a0, 0, 0, 0);
      f32x4 a1 = __builtin_amdgcn_mfma_f32_16x16x32_bf16(ah0, bh10, z, 0, 0, 0);
      a1 = __builtin_amdgcn_mfma_f32_16x16x32_bf16(ah1, bh11, a1, 0, 0, 0);

      const int c0 = cb + st * 16 + quad * 4;
      const int m0 = (a0[0] >= T0) | ((a0[1] >= T0) << 1) |
                     ((a0[2] >= T0) << 2) | ((a0[3] >= T0) << 3);
      if (m0) {
        int slot = atomicAdd(&lcnt[rl0], __popc(m0));  // LDS atomic, block-local
#pragma unroll
        for (int r = 0; r < 4; ++r)
          if (m0 & (1 << r)) {
            if (slot < LCAP) lst[rl0][slot] = (ushort_t)(c0 + r);
            ++slot;
          }
      }
      const int m1 = (a1[0] >= T1) | ((a1[1] >= T1) << 1) |
                     ((a1[2] >= T1) << 2) | ((a1[3] >= T1) << 3);
      if (m1) {
        int slot = atomicAdd(&lcnt[rl1], __popc(m1));
#pragma unroll
        for (int r = 0; r < 4; ++r)
          if (m1 & (1 << r)) {
            if (slot < LCAP) lst[rl1][slot] = (ushort_t)(c0 + r);
            ++slot;
          }
      }
    }
    __syncthreads();  // readers done before next stage overwrites
  }
  // flush: one global reservation per row, 128 rows by threads 0..127 (parallel atomics)
  if (tid < 128) {
    const int row = rb * 128 + tid;
    const int cnt = min(lcnt[tid], LCAP);
    int base = atomicAdd(rowcnt + row, cnt);
    for (int j = 0; j < cnt; ++j) {
      const int gs = base + j;
      if (gs < MAXC) cidx[(size_t)row * MAXC + gs] = (int)lst[tid][j];
    }
  }
}

// ---------------- K3: exact fp32 dots on candidates + top-16 + gather + mean ----------------
// wave per row; grid NROWS/4 = 4608 blocks x 4 waves.
// top-16 via 64-bit ballot-bisection (keys distinct => exactly 16 selected).
__global__ __launch_bounds__(256) void k_merge_gather(
    const float* __restrict__ nf, const int* __restrict__ cidx,
    const int* __restrict__ rowcnt, float* __restrict__ corr) {
  __shared__ ushort_t selc[4][TK];
  const int wave = threadIdx.x >> 6, lane = threadIdx.x & 63;
  const int row = blockIdx.x * 4 + wave;
  const int b = row >= NPIX;
  const int rl = row - b * NPIX;
  const float* nfb = nf + (size_t)b * NPIX * RC;
  const int C = min(rowcnt[row], MAXC);

  if (lane < TK) selc[wave][lane] = (ushort_t)rl;  // safety pad (C<16 impossible by construction)
  __syncthreads();

  float4 rv[16];
  const float4* r4 = (const float4*)(nf + (size_t)row * RC);
#pragma unroll
  for (int i = 0; i < 16; ++i) rv[i] = r4[i];  // broadcast loads

  const int* cp = cidx + (size_t)row * MAXC;
  unsigned long long k0 = 0, k1 = 0;
  int c0 = rl, c1 = rl;
  {
    c0 = (lane < C) ? cp[lane] : rl;
    const float4* g = (const float4*)(nfb + (size_t)c0 * RC);
    float s = 0.f;
#pragma unroll
    for (int i = 0; i < 16; ++i) {
      float4 a = g[i];
      s += a.x * rv[i].x + a.y * rv[i].y + a.z * rv[i].z + a.w * rv[i].w;
    }
    if (lane < C)
      k0 = ((unsigned long long)ordu(s) << 32) | (uint_t)(~(uint_t)c0);
  }
  if (C > 64) {  // wave-uniform branch, rare
    c1 = (64 + lane < C) ? cp[64 + lane] : rl;
    const float4* g = (const float4*)(nfb + (size_t)c1 * RC);
    float s = 0.f;
#pragma unroll
    for (int i = 0; i < 16; ++i) {
      float4 a = g[i];
      s += a.x * rv[i].x + a.y * rv[i].y + a.z * rv[i].z + a.w * rv[i].w;
    }
    if (64 + lane < C)
      k1 = ((unsigned long long)ordu(s) << 32) | (uint_t)(~(uint_t)c1);
  }

  // bisection: largest thr with |{keys >= thr}| >= 16; distinct keys => exactly 16
  unsigned long long thr = 0;
#pragma unroll
  for (int bit = 63; bit >= 0; --bit) {
    const unsigned long long cand = thr | (1ull << bit);
    const int cnt = __popcll(__ballot(k0 >= cand)) + __popcll(__ballot(k1 >= cand));
    if (cnt >= TK) thr = cand;
  }
  if (thr != 0) {  // thr==0 only if <16 keys total (impossible; pad stays)
    const unsigned long long ml = (lane == 0) ? 0ull : (~0ull >> (64 - lane));
    const unsigned long long b0 = __ballot(k0 >= thr);
    const unsigned long long b1 = __ballot(k1 >= thr);
    const int n0 = __popcll(b0);
    if (k0 >= thr) {
      const int r = __popcll(b0 & ml);
      if (r < TK) selc[wave][r] = (ushort_t)c0;
    }
    if (k1 >= thr) {
      const int r = n0 + __popcll(b1 & ml);
      if (r < TK) selc[wave][r] = (ushort_t)c1;
    }
  }
  __syncthreads();

  float acc = 0.f;
#pragma unroll
  for (int t = 0; t < TK; ++t)
    acc += nfb[(size_t)selc[wave][t] * RC + lane];  // coalesced 256B per t
  corr[(size_t)row * RC + lane] = acc * 0.0625f;
}

// ---------------- K4: proj back to C channels + residual add ----------------
// grid: 72 pixgroups x 8 channel-eighths = 576
__global__ __launch_bounds__(256) void k_proj_add(
    const float* __restrict__ x, const float* __restrict__ wp,
    const float* __restrict__ corr, float* __restrict__ out) {
  const int pg = blockIdx.x >> 3, cq = blockIdx.x & 7;
  const int tid = threadIdx.x;

  __shared__ float wl[32 * RC];  // 8 KB
  {
    const float4* src = (const float4*)(wp + (size_t)cq * 32 * RC);
    float4* dst = (float4*)wl;
#pragma unroll
    for (int i = 0; i < 2; ++i) dst[i * 256 + tid] = src[i * 256 + tid];
  }

  const int p = pg * 256 + tid;
  const int b = p >= NPIX;
  const int n = p - b * NPIX;

  float4 cr[16];
  const float4* c4 = (const float4*)(corr + (size_t)p * RC);
#pragma unroll
  for (int i = 0; i < 16; ++i) cr[i] = c4[i];
  __syncthreads();

  const size_t xb = (size_t)b * NC * NPIX + n;
  for (int cl = 0; cl < 32; ++cl) {
    const float4* w4 = (const float4*)(wl + cl * RC);  // broadcast
    float s = 0.f;
#pragma unroll
    for (int i = 0; i < 16; ++i) {
      float4 w = w4[i];
      s += w.x * cr[i].x + w.y * cr[i].y + w.z * cr[i].z + w.w * cr[i].w;
    }
    const int c = cq * 32 + cl;
    const size_t oi = xb + (size_t)c * NPIX;
    out[oi] = x[oi] + s;  // coalesced
  }
}

extern "C" void kernel_launch(void* const* d_in, const int* in_sizes, int n_in,
                              void* d_out, int out_size, void* d_ws, size_t ws_size,
                              hipStream_t stream) {
  const float* x = (const float*)d_in[0];
  const float* wr = (const float*)d_in[1];
  const float* wp = (const float*)d_in[2];
  float* out = (float*)d_out;

  char* ws = (char*)d_ws;
  // region1 (18,874,368 B) time-shares: feat4 (reduce->normsplit),
  // tmax (sim_max->thresh, 18432*96*4 = 7.1 MB), corr (merge->proj).
  float* feat4 = (float*)ws;
  float* tmax = (float*)ws;
  float* corr = (float*)ws;
  float* nf = (float*)(ws + 18874368);
  ushort_t* nf_hi = (ushort_t*)(ws + 23592960);
  float* Tb = (float*)(ws + 25952256);
  int* rowcnt = (int*)(ws + 26025984);
  int* cidx = (int*)(ws + 26099712);
  // total 35,536,896 B

  hipLaunchKernelGGL(k_reduce, dim3(1152), dim3(256), 0, stream, x, wr, feat4);
  hipLaunchKernelGGL(k_normsplit, dim3(288), dim3(256), 0, stream, feat4, nf, nf_hi);
  hipLaunchKernelGGL(k_sim_max, dim3(144 * NQ), dim3(256), 0, stream, nf_hi, tmax);
  hipLaunchKernelGGL(k_thresh, dim3(NROWS / 4), dim3(256), 0, stream, tmax, Tb);
  hipMemsetAsync(rowcnt, 0, NROWS * sizeof(int), stream);
  hipLaunchKernelGGL(k_collect, dim3(144 * NQ), dim3(256), 0, stream,
                     nf_hi, Tb, cidx, rowcnt);
  hipLaunchKernelGGL(k_merge_gather, dim3(NROWS / 4), dim3(256), 0, stream,
                     nf, cidx, rowcnt, corr);
  hipLaunchKernelGGL(k_proj_add, dim3(576), dim3(256), 0, stream, x, wp, corr, out);
}